// Round 2
// baseline (330.886 us; speedup 1.0000x reference)
//
#include <hip/hip_runtime.h>
#include <math.h>

// AttnBlock: GroupNorm(32) -> q,k,v 1x1 -> spatial attention -> proj -> resid.
// Round 11: KSPLIT back to 2 (R10 showed occupancy is register-capped at
// 2 waves/SIMD: ~100 VGPR + ~80 acc regs => only one 8-wave block/CU, so
// KSPLIT=4 only doubled epilogue traffic). New lever: q/k/v are written
// PRE-SWIZZLED to global by qkvg, so attn stages K/V/Q with async
// global_load_lds DMA (linear LDS image, rule #21). Tile loop is
// single-buffer two-phase: DMA K(t+1) after the QK barrier (hides under
// softmax+PV), DMA V(t+1) after the PV barrier (hides under next QK).
// __syncthreads() drains vmcnt, so no inline asm is needed. Removes the
// register prefetch (-32 VGPR) and all LDS-write instrs from the waves.

#define BB 4
#define CCH 256
#define NSP 4096
#define EPSV 1e-5f
#define ATTN_SCALE 0.0625f  // 256^-0.5
#define RSQRT2 0.70710678118654752440f
#define KSPLIT 2
#define TILES_PER_PART 32   // 4096 / 64 / KSPLIT

typedef __attribute__((ext_vector_type(8))) short bf16x8;
typedef __attribute__((ext_vector_type(4))) short bf16x4;
typedef __attribute__((ext_vector_type(4))) float f32x4;

typedef __attribute__((address_space(1))) void gvoid;
typedef __attribute__((address_space(3))) void lvoid;
__device__ __forceinline__ void dma16(const void* g, void* l) {
  __builtin_amdgcn_global_load_lds((gvoid*)g, (lvoid*)l, 16, 0, 0);
}

__device__ __forceinline__ short f2bf(float f) {
  union { float f; unsigned u; } a; a.f = f;
  unsigned r = a.u + 0x7fffu + ((a.u >> 16) & 1u);  // RTN-even
  return (short)(r >> 16);
}
__device__ __forceinline__ float bf2f(short s) {
  union { unsigned u; float f; } a;
  a.u = ((unsigned)(unsigned short)s) << 16;
  return a.f;
}

__device__ __forceinline__ f32x4 mfma16x16x16(bf16x4 a, bf16x4 b, f32x4 c) {
#if __has_builtin(__builtin_amdgcn_mfma_f32_16x16x16bf16_1k)
  return __builtin_amdgcn_mfma_f32_16x16x16bf16_1k(a, b, c, 0, 0, 0);
#else
  asm volatile("v_mfma_f32_16x16x16_bf16 %0, %1, %2, %0"
               : "+v"(c) : "v"(a), "v"(b));
  return c;
#endif
}

// ---------------- GroupNorm stats only: mean/rstd per (b,g) ----------------
__global__ __launch_bounds__(256) void gn_stats(
    const float* __restrict__ x, float* __restrict__ stats) {
  int b = blockIdx.x >> 5;
  int g = blockIdx.x & 31;
  size_t base = ((size_t)b * CCH + (size_t)g * 8) * NSP;
  const float4* xv = (const float4*)(x + base);
  int tid = threadIdx.x;
  float s = 0.f, ss = 0.f;
  for (int i = tid; i < 8192; i += 256) {
    float4 v = xv[i];
    s += (v.x + v.y) + (v.z + v.w);
    ss += (v.x * v.x + v.y * v.y) + (v.z * v.z + v.w * v.w);
  }
#pragma unroll
  for (int off = 32; off > 0; off >>= 1) {
    s += __shfl_down(s, off, 64);
    ss += __shfl_down(ss, off, 64);
  }
  __shared__ float rs[4], rss[4];
  int wv = tid >> 6;
  if ((tid & 63) == 0) { rs[wv] = s; rss[wv] = ss; }
  __syncthreads();
  if (tid == 0) {
    float S = rs[0] + rs[1] + rs[2] + rs[3];
    float SS = rss[0] + rss[1] + rss[2] + rss[3];
    float mean = S * (1.f / 32768.f);
    float var = SS * (1.f / 32768.f) - mean * mean;
    stats[(b * 32 + g) * 2 + 0] = mean;
    stats[(b * 32 + g) * 2 + 1] = rsqrtf(var + EPSV);
  }
}

// ------------- prep: W [c][d] fp32 -> [d][c] bf16, 4 weights --------------
__global__ __launch_bounds__(256) void prep_w(
    const float* __restrict__ Wq, const float* __restrict__ Wk,
    const float* __restrict__ Wv, const float* __restrict__ Wp,
    short* __restrict__ wts) {
  __shared__ float T[64][65];
  int c0 = blockIdx.x * 64, d0 = blockIdx.y * 64;
  int wz = blockIdx.z;
  const float* W = (wz == 0) ? Wq : (wz == 1) ? Wk : (wz == 2) ? Wv : Wp;
  short* wt = wts + (size_t)wz * CCH * CCH;
  int tid = threadIdx.x;
#pragma unroll
  for (int i = 0; i < 16; ++i) {
    int idx = tid + 256 * i;
    int row = idx >> 6, col = idx & 63;
    T[row][col] = W[(size_t)(c0 + row) * CCH + d0 + col];
  }
  __syncthreads();
#pragma unroll
  for (int i = 0; i < 16; ++i) {
    int idx = tid + 256 * i;
    int dr = idx >> 6, cc = idx & 63;
    wt[(size_t)(d0 + dr) * CCH + c0 + cc] = f2bf(T[cc][dr]);
  }
}

// ------- qkvg: fused GN-apply + q,k,v projections via bf16 MFMA -----------
// q/k outputs are written CHUNK-SWIZZLED: global[n][chunk x] holds source
// chunk (x&24)|((x&7)^(n&7)) (8-short chunks), so attn's LDS tile is a
// linear DMA copy. v output [c][n] swizzles key-chunks within each 64-key
// tile by (c&7).
__global__ __launch_bounds__(256) void qkvg_kernel(
    const float* __restrict__ x, const float* __restrict__ stats,
    const float* __restrict__ gw, const float* __restrict__ gb,
    const short* __restrict__ wqt, const short* __restrict__ wkt,
    const short* __restrict__ wvt,
    const float* __restrict__ bq, const float* __restrict__ bk,
    const float* __restrict__ bv,
    short* __restrict__ qo, short* __restrict__ ko, short* __restrict__ vo) {
  __shared__ __align__(16) unsigned char smem[52224];
  float (*Ts)[68] = (float(*)[68])smem;          // 64 x 68 fp32 (17408 B)
  float* aco = (float*)(smem + 17408);           // 256 f32
  float* bco = aco + 256;                        // 256 f32
  short* Hs = (short*)(smem + 19456);            // [64 n][256 c] swizzled bf16
  short* Fo = (short*)smem;                      // epilogue [64 n][264] bf16

  int bx = blockIdx.x;
  int b = bx & 3, n0 = (bx >> 2) * 64;
  int tid = threadIdx.x;
  {  // per-channel scale/shift
    int g = tid >> 3;
    float mean = stats[(b * 32 + g) * 2 + 0];
    float rstd = stats[(b * 32 + g) * 2 + 1];
    float a = gw[tid] * rstd;
    aco[tid] = a;
    bco[tid] = gb[tid] - mean * a;
  }
  __syncthreads();
  const float* xb = x + (size_t)b * CCH * NSP;
  // ---- 4 passes: load x chunk, normalize, transpose, bf16 -> swizzled Hs --
  for (int p = 0; p < 4; ++p) {
    int c0 = p * 64;
#pragma unroll
    for (int i = 0; i < 4; ++i) {
      int crow = (tid >> 4) + i * 16;
      int c = c0 + crow;
      float4 v = *(const float4*)&xb[(size_t)c * NSP + n0 + (tid & 15) * 4];
      float a = aco[c], bb = bco[c];
      v.x = v.x * a + bb; v.y = v.y * a + bb;
      v.z = v.z * a + bb; v.w = v.w * a + bb;
      *(float4*)&Ts[crow][(tid & 15) * 4] = v;   // Ts[c_local][n_local]
    }
    __syncthreads();
    {
      int n = tid >> 2, seg = tid & 3;
#pragma unroll
      for (int u = 0; u < 2; ++u) {
        int cb = seg * 16 + u * 8;
        bf16x8 r;
#pragma unroll
        for (int j = 0; j < 8; ++j) r[j] = f2bf(Ts[cb + j][n]);
        int chunk = (c0 + cb) >> 3;
        *(bf16x8*)(Hs + n * 256 + ((chunk ^ (n & 7)) * 8)) = r;
      }
    }
    __syncthreads();
  }
  // ---- extract B-frags (rows = this wave's 16 n) ----
  int w = tid >> 6, lane = tid & 63, quad = lane >> 4, l16 = lane & 15;
  bf16x8 a_h[8];
  {
    int row = w * 16 + l16;
#pragma unroll
    for (int kc = 0; kc < 8; ++kc)
      a_h[kc] = *(bf16x8*)(Hs + row * 256 + (((kc * 4 + quad) ^ (row & 7)) * 8));
  }
  __syncthreads();  // all waves extracted; smem reusable as Fo
  // ---- 3 projections ----
  for (int op = 0; op < 3; ++op) {
    const short* wt = (op == 0) ? wqt : (op == 1) ? wkt : wvt;
    const float* bias = (op == 0) ? bq : (op == 1) ? bk : bv;
    f32x4 acc[16];
#pragma unroll
    for (int mb = 0; mb < 16; ++mb) acc[mb] = (f32x4){0.f, 0.f, 0.f, 0.f};
#pragma unroll 4
    for (int mb = 0; mb < 16; ++mb) {
      const short* wp = wt + (size_t)(mb * 16 + l16) * CCH + quad * 8;
#pragma unroll
      for (int kc = 0; kc < 8; ++kc) {
        bf16x8 af = *(const bf16x8*)(wp + kc * 32);
        acc[mb] = __builtin_amdgcn_mfma_f32_16x16x32_bf16(af, a_h[kc], acc[mb], 0, 0, 0);
      }
    }
    int n = n0 + w * 16 + l16;
    if (op == 2) {  // v: [c][n] scalar stores, key-chunk swizzled by (d&7)
      short* ob = vo + (size_t)b * CCH * NSP;
      int nt = n & ~63, nl3 = n & 7, nc = (n >> 3) & 7;
#pragma unroll
      for (int mb = 0; mb < 16; ++mb)
#pragma unroll
        for (int r = 0; r < 4; ++r) {
          int d = mb * 16 + quad * 4 + r;
          int ns = nt | ((nc ^ (d & 7)) << 3) | nl3;
          ob[(size_t)d * NSP + ns] = f2bf(acc[mb][r] + bias[d]);
        }
    } else {  // q/k: transpose via Fo -> [n][c] b128 stores, chunk-swizzled
      float sc = (op == 0) ? ATTN_SCALE : 1.f;
      int nl = w * 16 + l16;
#pragma unroll
      for (int mb = 0; mb < 16; ++mb)
#pragma unroll
        for (int r = 0; r < 4; ++r) {
          int d = mb * 16 + quad * 4 + r;
          Fo[nl * 264 + d] = f2bf((acc[mb][r] + bias[d]) * sc);
        }
      __syncthreads();
      short* ob = ((op == 0) ? qo : ko) + (size_t)b * NSP * CCH;
#pragma unroll
      for (int it = 0; it < 2; ++it) {
        int idx = tid + 256 * it;
        int row = idx >> 3, seg = idx & 7, r7 = row & 7;
        short* dst = ob + (size_t)(n0 + row) * CCH + seg * 32;
#pragma unroll
        for (int i = 0; i < 4; ++i) {
          int xch = seg * 4 + i;
          int cs = (xch & 24) | ((xch & 7) ^ r7);  // source chunk for slot xch
          *(bf16x8*)(dst + i * 8) = *(bf16x8*)(Fo + row * 264 + cs * 8);
        }
      }
      __syncthreads();
    }
  }
}

// ------ flash attention: 8 waves, 16 q/wave, 128 q/block, DMA staging ------
// q,k: [b][n][c] bf16 chunk-swizzled (q pre-scaled); v: [b][c][n] bf16
// key-chunk swizzled. LDS tiles are linear DMA copies of global.
// Writes NORMALIZED partial O [kh][b][n][c] bf16 + m,l stats [kh][b][n].
__global__ __launch_bounds__(512, 1) void attn_kernel(
    const short* __restrict__ q, const short* __restrict__ k,
    const short* __restrict__ v, short* __restrict__ po,
    float* __restrict__ pm, float* __restrict__ pl) {
  __shared__ __align__(16) unsigned char smem[65536];   // 64 KB
  short* Ks = (short*)smem;            // [64 m][256 c] swizzled image
  short* Vs = (short*)(smem + 32768);  // [256 c][64 m] swizzled image
  short* Fo = (short*)smem;            // epilogue [64 n][264 c] bf16

  int bx = blockIdx.x;
  int b = bx & 3;
  int n0 = ((bx >> 2) & 31) << 7;   // 128-query block
  int kh = bx >> 7;                 // key half
  const short* qb = q + (size_t)b * NSP * CCH;
  const short* kb = k + (size_t)b * NSP * CCH;
  const char*  vbB = (const char*)(v + (size_t)b * CCH * NSP);
  int tid = threadIdx.x;
  int w = tid >> 6, lane = tid & 63, quad = lane >> 4, l16 = lane & 15;
  int mbase = kh * TILES_PER_PART * 64;

  // ---- prologue: DMA V0 + Q pass0; extract Q frags; K0 ----
#pragma unroll
  for (int i = 0; i < 4; ++i) {      // V tile 0: 32 KB, [c][64 keys]
    int off = tid * 16 + i * 8192;
    int c = off >> 7, inrow = off & 127;
    dma16(vbB + (size_t)c * (NSP * 2) + (size_t)mbase * 2 + inrow,
          (char*)Vs + off);
  }
#pragma unroll
  for (int i = 0; i < 4; ++i) {      // Q rows n0..n0+63
    int off = tid * 16 + i * 8192;
    dma16((const char*)(qb + (size_t)n0 * CCH) + off, (char*)Ks + off);
  }
  __syncthreads();
  bf16x8 a_q[8];
  if ((w >> 2) == 0) {
    int row = (w & 3) * 16 + l16;
#pragma unroll
    for (int kc = 0; kc < 8; ++kc)
      a_q[kc] = *(bf16x8*)(Ks + row * 256 + (((kc * 4 + quad) ^ (row & 7)) * 8));
  }
  __syncthreads();
#pragma unroll
  for (int i = 0; i < 4; ++i) {      // Q rows n0+64..n0+127
    int off = tid * 16 + i * 8192;
    dma16((const char*)(qb + (size_t)(n0 + 64) * CCH) + off, (char*)Ks + off);
  }
  __syncthreads();
  if ((w >> 2) == 1) {
    int row = (w & 3) * 16 + l16;
#pragma unroll
    for (int kc = 0; kc < 8; ++kc)
      a_q[kc] = *(bf16x8*)(Ks + row * 256 + (((kc * 4 + quad) ^ (row & 7)) * 8));
  }
  __syncthreads();
#pragma unroll
  for (int i = 0; i < 4; ++i) {      // K tile 0
    int off = tid * 16 + i * 8192;
    dma16((const char*)(kb + (size_t)mbase * CCH) + off, (char*)Ks + off);
  }
  __syncthreads();                   // drains K0

  f32x4 accO[16];  // O^T C-layout: ch = cb*16 + quad*4 + r, query = w*16+l16
#pragma unroll
  for (int cb = 0; cb < 16; ++cb) accO[cb] = (f32x4){0.f, 0.f, 0.f, 0.f};
  float m_run = -1e30f, l_run = 0.f;

#pragma unroll 1
  for (int t = 0; t < TILES_PER_PART; ++t) {
    // ---- S^T = K Q^T : rows = 64 keys, cols = this wave's 16 queries ----
    f32x4 s[4];
#pragma unroll
    for (int mb = 0; mb < 4; ++mb) s[mb] = (f32x4){0.f, 0.f, 0.f, 0.f};
#pragma unroll
    for (int kc = 0; kc < 8; ++kc) {
#pragma unroll
      for (int mb = 0; mb < 4; ++mb) {
        int row = mb * 16 + l16;
        bf16x8 kf = *(bf16x8*)(Ks + row * 256 + (((kc * 4 + quad) ^ (row & 7)) * 8));
        s[mb] = __builtin_amdgcn_mfma_f32_16x16x32_bf16(kf, a_q[kc], s[mb], 0, 0, 0);
      }
    }
    __syncthreads();  // all waves done reading Ks (drains V(t) DMA too)
    if (t < TILES_PER_PART - 1) {  // DMA K(t+1): overlaps softmax + PV
      const char* kp = (const char*)(kb + (size_t)(mbase + (t + 1) * 64) * CCH);
#pragma unroll
      for (int i = 0; i < 4; ++i) {
        int off = tid * 16 + i * 8192;
        dma16(kp + off, (char*)Ks + off);
      }
    }
    // ---- online softmax: per-lane scalar stats (one query per lane) ----
    float mx = -1e30f;
#pragma unroll
    for (int mb = 0; mb < 4; ++mb)
#pragma unroll
      for (int r = 0; r < 4; ++r) mx = fmaxf(mx, s[mb][r]);
    mx = fmaxf(mx, __shfl_xor(mx, 16));
    mx = fmaxf(mx, __shfl_xor(mx, 32));
    float mnew = fmaxf(m_run, mx);
    float alpha = __expf(m_run - mnew);
    m_run = mnew;
    float ls = 0.f;
    bf16x4 pb[4];
#pragma unroll
    for (int mb = 0; mb < 4; ++mb)
#pragma unroll
      for (int r = 0; r < 4; ++r) {
        float p = __expf(s[mb][r] - mnew);
        ls += p;
        pb[mb][r] = f2bf(p);
      }
    ls += __shfl_xor(ls, 16);
    ls += __shfl_xor(ls, 32);
    l_run = l_run * alpha + ls;
#pragma unroll
    for (int cb = 0; cb < 16; ++cb) accO[cb] *= alpha;
    // ---- O^T += V P^T : A = V-frag (b64), B = pb from registers ----
#pragma unroll
    for (int kw = 0; kw < 4; ++kw) {
#pragma unroll
      for (int cb = 0; cb < 16; ++cb) {
        int row = cb * 16 + l16;
        int chunk = (kw * 2 + (quad >> 1)) ^ (row & 7);
        bf16x4 vf = *(bf16x4*)(Vs + row * 64 + chunk * 8 + (quad & 1) * 4);
        accO[cb] = mfma16x16x16(vf, pb[kw], accO[cb]);
      }
    }
    __syncthreads();  // all waves done reading Vs (drains K(t+1) DMA too)
    if (t < TILES_PER_PART - 1) {  // DMA V(t+1): overlaps next QK + softmax
      int m0 = mbase + (t + 1) * 64;
#pragma unroll
      for (int i = 0; i < 4; ++i) {
        int off = tid * 16 + i * 8192;
        int c = off >> 7, inrow = off & 127;
        dma16(vbB + (size_t)c * (NSP * 2) + (size_t)m0 * 2 + inrow,
              (char*)Vs + off);
      }
    }
  }
  // ---- stats ----
  size_t sbase = ((size_t)kh * BB + b) * NSP + n0;
  if (quad == 0) {
    pm[sbase + w * 16 + l16] = m_run;
    pl[sbase + w * 16 + l16] = l_run;
  }
  // ---- epilogue: normalized bf16 O -> po [kh][b][n][c], LDS transpose ----
  float linv = 1.f / l_run;
  short* ob = po + ((size_t)kh * BB + b) * NSP * CCH;
#pragma unroll
  for (int p = 0; p < 2; ++p) {
    __syncthreads();
    if ((w >> 2) == p) {
      int nloc = (w & 3) * 16 + l16;
#pragma unroll
      for (int cb = 0; cb < 16; ++cb)
#pragma unroll
        for (int r = 0; r < 4; ++r)
          Fo[nloc * 264 + cb * 16 + quad * 4 + r] = f2bf(accO[cb][r] * linv);
    }
    __syncthreads();
    int row = tid >> 3, seg = tid & 7;
    short* dst = ob + (size_t)(n0 + p * 64 + row) * CCH + seg * 32;
#pragma unroll
    for (int i = 0; i < 4; ++i)
      *(bf16x8*)(dst + i * 8) = *(bf16x8*)(Fo + row * 264 + seg * 32 + i * 8);
  }
}

// ------- proj: frag-direct MFMA, KSPLIT-way merge in registers, +bias+resid -
__global__ __launch_bounds__(256) void proj_kernel(
    const short* __restrict__ po, const float* __restrict__ pm,
    const float* __restrict__ pl, const short* __restrict__ wpt,
    const float* __restrict__ bp, const float* __restrict__ x,
    float* __restrict__ out) {
  int n0 = blockIdx.x * 64;
  int dh = blockIdx.y * 128;
  int b = blockIdx.z;
  int tid = threadIdx.x;
  int w = tid >> 6, lane = tid & 63, quad = lane >> 4, l16 = lane & 15;
  int n = n0 + w * 16 + l16;

  float wgt[KSPLIT];
  {
    float m[KSPLIT];
    float M = -1e30f;
#pragma unroll
    for (int s = 0; s < KSPLIT; ++s) {
      m[s] = pm[((size_t)s * BB + b) * NSP + n];
      M = fmaxf(M, m[s]);
    }
    float wsum = 0.f;
#pragma unroll
    for (int s = 0; s < KSPLIT; ++s) {
      wgt[s] = __expf(m[s] - M) * pl[((size_t)s * BB + b) * NSP + n];
      wsum += wgt[s];
    }
    float linv = 1.f / wsum;
#pragma unroll
    for (int s = 0; s < KSPLIT; ++s) wgt[s] *= linv;
  }

  f32x4 acc[8];
#pragma unroll
  for (int mb = 0; mb < 8; ++mb) acc[mb] = (f32x4){0.f, 0.f, 0.f, 0.f};

  const short* pob = po + ((size_t)b * NSP + n) * CCH;
#pragma unroll 2
  for (int kc = 0; kc < 8; ++kc) {
    int coff = kc * 32 + quad * 8;
    float e[8];
#pragma unroll
    for (int i = 0; i < 8; ++i) e[i] = 0.f;
#pragma unroll
    for (int s = 0; s < KSPLIT; ++s) {
      bf16x8 f = *(const bf16x8*)(pob + (size_t)s * BB * NSP * CCH + coff);
#pragma unroll
      for (int i = 0; i < 8; ++i) e[i] += wgt[s] * bf2f(f[i]);
    }
    bf16x8 bm;
#pragma unroll
    for (int i = 0; i < 8; ++i) bm[i] = f2bf(e[i]);
#pragma unroll
    for (int mb = 0; mb < 8; ++mb) {
      bf16x8 af = *(const bf16x8*)(wpt + (size_t)(dh + mb * 16 + l16) * CCH + coff);
      acc[mb] = __builtin_amdgcn_mfma_f32_16x16x32_bf16(af, bm, acc[mb], 0, 0, 0);
    }
  }
#pragma unroll
  for (int mb = 0; mb < 8; ++mb) {
#pragma unroll
    for (int r = 0; r < 4; ++r) {
      int d = dh + mb * 16 + quad * 4 + r;
      size_t off = ((size_t)b * CCH + d) * NSP + n;
      out[off] = (acc[mb][r] + bp[d] + x[off]) * RSQRT2;
    }
  }
}

extern "C" void kernel_launch(void* const* d_in, const int* in_sizes, int n_in,
                              void* d_out, int out_size, void* d_ws, size_t ws_size,
                              hipStream_t stream) {
  const float* x  = (const float*)d_in[0];
  const float* gw = (const float*)d_in[1];
  const float* gb = (const float*)d_in[2];
  const float* Wq = (const float*)d_in[3];
  const float* bq = (const float*)d_in[4];
  const float* Wk = (const float*)d_in[5];
  const float* bk = (const float*)d_in[6];
  const float* Wv = (const float*)d_in[7];
  const float* bv = (const float*)d_in[8];
  const float* Wp = (const float*)d_in[9];
  const float* bp = (const float*)d_in[10];
  float* out = (float*)d_out;

  const size_t SZ = (size_t)BB * CCH * NSP;  // 4.19M elems
  short* qb  = (short*)d_ws;                 // bf16 [b][n][c] swizzled, scaled
  short* kb  = qb + SZ;                      // bf16 [b][n][c] swizzled
  short* vb  = kb + SZ;                      // bf16 [b][c][n] swizzled
  short* poT = vb + SZ;                      // bf16 [KSPLIT][b][n][c] normalized
  float* pm  = (float*)(poT + (size_t)KSPLIT * SZ);  // [KSPLIT][b][n]
  float* pl  = pm + (size_t)KSPLIT * BB * NSP;
  float* stats = pl + (size_t)KSPLIT * BB * NSP;     // [b][32][2]
  short* wts = (short*)(stats + BB * 64);            // bf16 [4][256][256]
  short* wqt = wts;
  short* wkt = wts + (size_t)CCH * CCH;
  short* wvt = wts + (size_t)2 * CCH * CCH;
  short* wpt = wts + (size_t)3 * CCH * CCH;

  gn_stats<<<dim3(BB * 32), dim3(256), 0, stream>>>(x, stats);
  prep_w<<<dim3(4, 4, 4), dim3(256), 0, stream>>>(Wq, Wk, Wv, Wp, wts);
  qkvg_kernel<<<dim3(256), dim3(256), 0, stream>>>(
      x, stats, gw, gb, wqt, wkt, wvt, bq, bk, bv, qb, kb, vb);
  attn_kernel<<<dim3(BB * 32 * KSPLIT), dim3(512), 0, stream>>>(
      qb, kb, vb, poT, pm, pl);
  proj_kernel<<<dim3(64, 2, BB), dim3(256), 0, stream>>>(
      poT, pm, pl, wpt, bp, x, out);
}

// Round 3
// 288.983 us; speedup vs baseline: 1.1450x; 1.1450x over previous
//
#include <hip/hip_runtime.h>
#include <math.h>

// AttnBlock: GroupNorm(32) -> q,k,v 1x1 -> spatial attention -> proj -> resid.
// Round 12: PV moves to full-rate 16x16x32 MFMA (was 64x half-rate 16x16x16).
// Trick: V's key-columns are stored PERMUTED in global (baked into qkvg's
// v-write, free), chosen so QK's C-layout output s[mb][r] maps directly into
// 16x16x32 B-frags with ZERO cross-lane shuffles:
//   permkey pk = (mb&1)*32 + quad*8 + (mb>>1)*4 + r
//   pw[g] = {s[g][0..3], s[g+2][0..3]}  (bf16)
// PV: 32 MFMA + 32 b128 V-reads per wave/tile (was 64 MFMA + 64 b64 reads).
// Also: T13 defer-rescale (skip accO*alpha when max doesn't grow by >8),
// T12 v_cvt_pk_bf16_f32 packing, T5 s_setprio around MFMA clusters.
// Staging stays DMA (global_load_lds) with pre-swizzled q/k/v images.

#define BB 4
#define CCH 256
#define NSP 4096
#define EPSV 1e-5f
#define ATTN_SCALE 0.0625f  // 256^-0.5
#define RSQRT2 0.70710678118654752440f
#define KSPLIT 2
#define TILES_PER_PART 32   // 4096 / 64 / KSPLIT

typedef __attribute__((ext_vector_type(8))) short bf16x8;
typedef __attribute__((ext_vector_type(4))) float f32x4;

typedef __attribute__((address_space(1))) void gvoid;
typedef __attribute__((address_space(3))) void lvoid;
__device__ __forceinline__ void dma16(const void* g, void* l) {
  __builtin_amdgcn_global_load_lds((gvoid*)g, (lvoid*)l, 16, 0, 0);
}

__device__ __forceinline__ short f2bf(float f) {
  union { float f; unsigned u; } a; a.f = f;
  unsigned r = a.u + 0x7fffu + ((a.u >> 16) & 1u);  // RTN-even
  return (short)(r >> 16);
}
__device__ __forceinline__ float bf2f(short s) {
  union { unsigned u; float f; } a;
  a.u = ((unsigned)(unsigned short)s) << 16;
  return a.f;
}
__device__ __forceinline__ unsigned cvt_pk_bf16(float lo, float hi) {
  unsigned r;
  asm("v_cvt_pk_bf16_f32 %0, %1, %2" : "=v"(r) : "v"(lo), "v"(hi));
  return r;
}

// ---------------- GroupNorm stats only: mean/rstd per (b,g) ----------------
__global__ __launch_bounds__(256) void gn_stats(
    const float* __restrict__ x, float* __restrict__ stats) {
  int b = blockIdx.x >> 5;
  int g = blockIdx.x & 31;
  size_t base = ((size_t)b * CCH + (size_t)g * 8) * NSP;
  const float4* xv = (const float4*)(x + base);
  int tid = threadIdx.x;
  float s = 0.f, ss = 0.f;
  for (int i = tid; i < 8192; i += 256) {
    float4 v = xv[i];
    s += (v.x + v.y) + (v.z + v.w);
    ss += (v.x * v.x + v.y * v.y) + (v.z * v.z + v.w * v.w);
  }
#pragma unroll
  for (int off = 32; off > 0; off >>= 1) {
    s += __shfl_down(s, off, 64);
    ss += __shfl_down(ss, off, 64);
  }
  __shared__ float rs[4], rss[4];
  int wv = tid >> 6;
  if ((tid & 63) == 0) { rs[wv] = s; rss[wv] = ss; }
  __syncthreads();
  if (tid == 0) {
    float S = rs[0] + rs[1] + rs[2] + rs[3];
    float SS = rss[0] + rss[1] + rss[2] + rss[3];
    float mean = S * (1.f / 32768.f);
    float var = SS * (1.f / 32768.f) - mean * mean;
    stats[(b * 32 + g) * 2 + 0] = mean;
    stats[(b * 32 + g) * 2 + 1] = rsqrtf(var + EPSV);
  }
}

// ------------- prep: W [c][d] fp32 -> [d][c] bf16, 4 weights --------------
__global__ __launch_bounds__(256) void prep_w(
    const float* __restrict__ Wq, const float* __restrict__ Wk,
    const float* __restrict__ Wv, const float* __restrict__ Wp,
    short* __restrict__ wts) {
  __shared__ float T[64][65];
  int c0 = blockIdx.x * 64, d0 = blockIdx.y * 64;
  int wz = blockIdx.z;
  const float* W = (wz == 0) ? Wq : (wz == 1) ? Wk : (wz == 2) ? Wv : Wp;
  short* wt = wts + (size_t)wz * CCH * CCH;
  int tid = threadIdx.x;
#pragma unroll
  for (int i = 0; i < 16; ++i) {
    int idx = tid + 256 * i;
    int row = idx >> 6, col = idx & 63;
    T[row][col] = W[(size_t)(c0 + row) * CCH + d0 + col];
  }
  __syncthreads();
#pragma unroll
  for (int i = 0; i < 16; ++i) {
    int idx = tid + 256 * i;
    int dr = idx >> 6, cc = idx & 63;
    wt[(size_t)(d0 + dr) * CCH + c0 + cc] = f2bf(T[cc][dr]);
  }
}

// ------- qkvg: fused GN-apply + q,k,v projections via bf16 MFMA -----------
// q/k outputs chunk-swizzled for linear DMA into attn's LDS. v output [c][n]
// stores, within each 64-key tile, key mm at permuted position:
//   pk = ((mb&1)<<5)|(q<<3)|((mb>>1)<<2)|r   (mm = mb*16+q*4+r)
// then bank-swizzles the 8-key chunk by (c&7). This makes QK's s[mb][r]
// a direct 16x16x32 B-frag for PV (see attn_kernel).
__global__ __launch_bounds__(256) void qkvg_kernel(
    const float* __restrict__ x, const float* __restrict__ stats,
    const float* __restrict__ gw, const float* __restrict__ gb,
    const short* __restrict__ wqt, const short* __restrict__ wkt,
    const short* __restrict__ wvt,
    const float* __restrict__ bq, const float* __restrict__ bk,
    const float* __restrict__ bv,
    short* __restrict__ qo, short* __restrict__ ko, short* __restrict__ vo) {
  __shared__ __align__(16) unsigned char smem[52224];
  float (*Ts)[68] = (float(*)[68])smem;          // 64 x 68 fp32 (17408 B)
  float* aco = (float*)(smem + 17408);           // 256 f32
  float* bco = aco + 256;                        // 256 f32
  short* Hs = (short*)(smem + 19456);            // [64 n][256 c] swizzled bf16
  short* Fo = (short*)smem;                      // epilogue [64 n][264] bf16

  int bx = blockIdx.x;
  int b = bx & 3, n0 = (bx >> 2) * 64;
  int tid = threadIdx.x;
  {  // per-channel scale/shift
    int g = tid >> 3;
    float mean = stats[(b * 32 + g) * 2 + 0];
    float rstd = stats[(b * 32 + g) * 2 + 1];
    float a = gw[tid] * rstd;
    aco[tid] = a;
    bco[tid] = gb[tid] - mean * a;
  }
  __syncthreads();
  const float* xb = x + (size_t)b * CCH * NSP;
  // ---- 4 passes: load x chunk, normalize, transpose, bf16 -> swizzled Hs --
  for (int p = 0; p < 4; ++p) {
    int c0 = p * 64;
#pragma unroll
    for (int i = 0; i < 4; ++i) {
      int crow = (tid >> 4) + i * 16;
      int c = c0 + crow;
      float4 v = *(const float4*)&xb[(size_t)c * NSP + n0 + (tid & 15) * 4];
      float a = aco[c], bb = bco[c];
      v.x = v.x * a + bb; v.y = v.y * a + bb;
      v.z = v.z * a + bb; v.w = v.w * a + bb;
      *(float4*)&Ts[crow][(tid & 15) * 4] = v;   // Ts[c_local][n_local]
    }
    __syncthreads();
    {
      int n = tid >> 2, seg = tid & 3;
#pragma unroll
      for (int u = 0; u < 2; ++u) {
        int cb = seg * 16 + u * 8;
        bf16x8 r;
#pragma unroll
        for (int j = 0; j < 8; ++j) r[j] = f2bf(Ts[cb + j][n]);
        int chunk = (c0 + cb) >> 3;
        *(bf16x8*)(Hs + n * 256 + ((chunk ^ (n & 7)) * 8)) = r;
      }
    }
    __syncthreads();
  }
  // ---- extract B-frags (rows = this wave's 16 n) ----
  int w = tid >> 6, lane = tid & 63, quad = lane >> 4, l16 = lane & 15;
  bf16x8 a_h[8];
  {
    int row = w * 16 + l16;
#pragma unroll
    for (int kc = 0; kc < 8; ++kc)
      a_h[kc] = *(bf16x8*)(Hs + row * 256 + (((kc * 4 + quad) ^ (row & 7)) * 8));
  }
  __syncthreads();  // all waves extracted; smem reusable as Fo
  // ---- 3 projections ----
  for (int op = 0; op < 3; ++op) {
    const short* wt = (op == 0) ? wqt : (op == 1) ? wkt : wvt;
    const float* bias = (op == 0) ? bq : (op == 1) ? bk : bv;
    f32x4 acc[16];
#pragma unroll
    for (int mb = 0; mb < 16; ++mb) acc[mb] = (f32x4){0.f, 0.f, 0.f, 0.f};
#pragma unroll 4
    for (int mb = 0; mb < 16; ++mb) {
      const short* wp = wt + (size_t)(mb * 16 + l16) * CCH + quad * 8;
#pragma unroll
      for (int kc = 0; kc < 8; ++kc) {
        bf16x8 af = *(const bf16x8*)(wp + kc * 32);
        acc[mb] = __builtin_amdgcn_mfma_f32_16x16x32_bf16(af, a_h[kc], acc[mb], 0, 0, 0);
      }
    }
    int n = n0 + w * 16 + l16;
    if (op == 2) {  // v: [c][n-permuted] scalar stores
      short* ob = vo + (size_t)b * CCH * NSP;
      int mm = n & 63, m0_ = n & ~63;
      int mb_ = mm >> 4, qq = (mm >> 2) & 3, rr2 = mm & 3;
      int lc = (mb_ & 1) * 4 + qq;          // logical 8-key chunk
      int jj = (mb_ >> 1) * 4 + rr2;        // slot within chunk
      int basen = m0_ + jj;
#pragma unroll
      for (int mb = 0; mb < 16; ++mb)
#pragma unroll
        for (int r = 0; r < 4; ++r) {
          int d = mb * 16 + quad * 4 + r;
          ob[(size_t)d * NSP + basen + ((lc ^ (d & 7)) << 3)] =
              f2bf(acc[mb][r] + bias[d]);
        }
    } else {  // q/k: transpose via Fo -> [n][c] b128 stores, chunk-swizzled
      float sc = (op == 0) ? ATTN_SCALE : 1.f;
      int nl = w * 16 + l16;
#pragma unroll
      for (int mb = 0; mb < 16; ++mb)
#pragma unroll
        for (int r = 0; r < 4; ++r) {
          int d = mb * 16 + quad * 4 + r;
          Fo[nl * 264 + d] = f2bf((acc[mb][r] + bias[d]) * sc);
        }
      __syncthreads();
      short* ob = ((op == 0) ? qo : ko) + (size_t)b * NSP * CCH;
#pragma unroll
      for (int it = 0; it < 2; ++it) {
        int idx = tid + 256 * it;
        int row = idx >> 3, seg = idx & 7, r7 = row & 7;
        short* dst = ob + (size_t)(n0 + row) * CCH + seg * 32;
#pragma unroll
        for (int i = 0; i < 4; ++i) {
          int xch = seg * 4 + i;
          int cs = (xch & 24) | ((xch & 7) ^ r7);  // source chunk for slot xch
          *(bf16x8*)(dst + i * 8) = *(bf16x8*)(Fo + row * 264 + cs * 8);
        }
      }
      __syncthreads();
    }
  }
}

// ------ flash attention: 8 waves, 16 q/wave, 128 q/block, DMA staging ------
// q,k: [b][n][c] bf16 chunk-swizzled (q pre-scaled); v: [b][c][n] bf16
// key-permuted + chunk-swizzled. LDS tiles are linear DMA copies of global.
// PV runs at full-rate 16x16x32: pw[g] = {exp(s[g]), exp(s[g+2])} feeds the
// B-operand directly thanks to the key permutation baked into v.
__global__ __launch_bounds__(512, 1) void attn_kernel(
    const short* __restrict__ q, const short* __restrict__ k,
    const short* __restrict__ v, short* __restrict__ po,
    float* __restrict__ pm, float* __restrict__ pl) {
  __shared__ __align__(16) unsigned char smem[65536];   // 64 KB
  short* Ks = (short*)smem;            // [64 m][256 c] swizzled image
  short* Vs = (short*)(smem + 32768);  // [256 c][64 m] permuted image
  short* Fo = (short*)smem;            // epilogue [64 n][264 c] bf16

  int bx = blockIdx.x;
  int b = bx & 3;
  int n0 = ((bx >> 2) & 31) << 7;   // 128-query block
  int kh = bx >> 7;                 // key half
  const short* qb = q + (size_t)b * NSP * CCH;
  const short* kb = k + (size_t)b * NSP * CCH;
  const char*  vbB = (const char*)(v + (size_t)b * CCH * NSP);
  int tid = threadIdx.x;
  int w = tid >> 6, lane = tid & 63, quad = lane >> 4, l16 = lane & 15;
  int mbase = kh * TILES_PER_PART * 64;

  // ---- prologue: DMA V0 + Q pass0; extract Q frags; K0 ----
#pragma unroll
  for (int i = 0; i < 4; ++i) {      // V tile 0: 32 KB, [c][64 keys]
    int off = tid * 16 + i * 8192;
    int c = off >> 7, inrow = off & 127;
    dma16(vbB + (size_t)c * (NSP * 2) + (size_t)mbase * 2 + inrow,
          (char*)Vs + off);
  }
#pragma unroll
  for (int i = 0; i < 4; ++i) {      // Q rows n0..n0+63
    int off = tid * 16 + i * 8192;
    dma16((const char*)(qb + (size_t)n0 * CCH) + off, (char*)Ks + off);
  }
  __syncthreads();
  bf16x8 a_q[8];
  if ((w >> 2) == 0) {
    int row = (w & 3) * 16 + l16;
#pragma unroll
    for (int kc = 0; kc < 8; ++kc)
      a_q[kc] = *(bf16x8*)(Ks + row * 256 + (((kc * 4 + quad) ^ (row & 7)) * 8));
  }
  __syncthreads();
#pragma unroll
  for (int i = 0; i < 4; ++i) {      // Q rows n0+64..n0+127
    int off = tid * 16 + i * 8192;
    dma16((const char*)(qb + (size_t)(n0 + 64) * CCH) + off, (char*)Ks + off);
  }
  __syncthreads();
  if ((w >> 2) == 1) {
    int row = (w & 3) * 16 + l16;
#pragma unroll
    for (int kc = 0; kc < 8; ++kc)
      a_q[kc] = *(bf16x8*)(Ks + row * 256 + (((kc * 4 + quad) ^ (row & 7)) * 8));
  }
  __syncthreads();
#pragma unroll
  for (int i = 0; i < 4; ++i) {      // K tile 0
    int off = tid * 16 + i * 8192;
    dma16((const char*)(kb + (size_t)mbase * CCH) + off, (char*)Ks + off);
  }
  __syncthreads();                   // drains K0

  f32x4 accO[16];  // O^T C-layout: ch = cb*16 + quad*4 + r, query = w*16+l16
#pragma unroll
  for (int cb = 0; cb < 16; ++cb) accO[cb] = (f32x4){0.f, 0.f, 0.f, 0.f};
  float m_run = -1e30f, l_run = 0.f;
  int pc0 = quad ^ (l16 & 7);        // V chunk for key-group 0 (loop-invariant)
  int pc1 = (4 + quad) ^ (l16 & 7);  // key-group 1

#pragma unroll 1
  for (int t = 0; t < TILES_PER_PART; ++t) {
    // ---- S^T = K Q^T : rows = 64 keys, cols = this wave's 16 queries ----
    f32x4 s[4];
#pragma unroll
    for (int mb = 0; mb < 4; ++mb) s[mb] = (f32x4){0.f, 0.f, 0.f, 0.f};
    __builtin_amdgcn_s_setprio(1);
#pragma unroll
    for (int kc = 0; kc < 8; ++kc) {
#pragma unroll
      for (int mb = 0; mb < 4; ++mb) {
        int row = mb * 16 + l16;
        bf16x8 kf = *(bf16x8*)(Ks + row * 256 + (((kc * 4 + quad) ^ (row & 7)) * 8));
        s[mb] = __builtin_amdgcn_mfma_f32_16x16x32_bf16(kf, a_q[kc], s[mb], 0, 0, 0);
      }
    }
    __builtin_amdgcn_s_setprio(0);
    __syncthreads();  // all waves done reading Ks (drains V(t) DMA too)
    if (t < TILES_PER_PART - 1) {  // DMA K(t+1): overlaps softmax + PV
      const char* kp = (const char*)(kb + (size_t)(mbase + (t + 1) * 64) * CCH);
#pragma unroll
      for (int i = 0; i < 4; ++i) {
        int off = tid * 16 + i * 8192;
        dma16(kp + off, (char*)Ks + off);
      }
    }
    // ---- online softmax: per-lane scalar stats (one query per lane) ----
    float mx = -1e30f;
#pragma unroll
    for (int mb = 0; mb < 4; ++mb)
#pragma unroll
      for (int r = 0; r < 4; ++r) mx = fmaxf(mx, s[mb][r]);
    mx = fmaxf(mx, __shfl_xor(mx, 16));
    mx = fmaxf(mx, __shfl_xor(mx, 32));
    if (!__all(mx - m_run <= 8.f)) {   // T13: rescale only when max grows >8
      float mnew = fmaxf(m_run, mx);
      float alpha = __expf(m_run - mnew);
#pragma unroll
      for (int cb = 0; cb < 16; ++cb) accO[cb] *= alpha;
      l_run *= alpha;
      m_run = mnew;
    }
    float ls = 0.f;
#pragma unroll
    for (int mb = 0; mb < 4; ++mb)
#pragma unroll
      for (int r = 0; r < 4; ++r) {
        float p = __expf(s[mb][r] - m_run);   // bounded by e^8
        ls += p;
        s[mb][r] = p;
      }
    ls += __shfl_xor(ls, 16);
    ls += __shfl_xor(ls, 32);
    l_run += ls;
    // ---- pack P into 16x16x32 B-frags (key permutation makes this direct) --
    union { unsigned u[4]; bf16x8 v; } pw0, pw1;
    pw0.u[0] = cvt_pk_bf16(s[0][0], s[0][1]);
    pw0.u[1] = cvt_pk_bf16(s[0][2], s[0][3]);
    pw0.u[2] = cvt_pk_bf16(s[2][0], s[2][1]);
    pw0.u[3] = cvt_pk_bf16(s[2][2], s[2][3]);
    pw1.u[0] = cvt_pk_bf16(s[1][0], s[1][1]);
    pw1.u[1] = cvt_pk_bf16(s[1][2], s[1][3]);
    pw1.u[2] = cvt_pk_bf16(s[3][0], s[3][1]);
    pw1.u[3] = cvt_pk_bf16(s[3][2], s[3][3]);
    // ---- O^T += V P^T : full-rate 16x16x32, b128 V reads ----
    __builtin_amdgcn_s_setprio(1);
#pragma unroll
    for (int cb = 0; cb < 16; ++cb) {
      bf16x8 vf = *(bf16x8*)(Vs + (cb * 16 + l16) * 64 + pc0 * 8);
      accO[cb] = __builtin_amdgcn_mfma_f32_16x16x32_bf16(vf, pw0.v, accO[cb], 0, 0, 0);
    }
#pragma unroll
    for (int cb = 0; cb < 16; ++cb) {
      bf16x8 vf = *(bf16x8*)(Vs + (cb * 16 + l16) * 64 + pc1 * 8);
      accO[cb] = __builtin_amdgcn_mfma_f32_16x16x32_bf16(vf, pw1.v, accO[cb], 0, 0, 0);
    }
    __builtin_amdgcn_s_setprio(0);
    __syncthreads();  // all waves done reading Vs (drains K(t+1) DMA too)
    if (t < TILES_PER_PART - 1) {  // DMA V(t+1): overlaps next QK + softmax
      int m0 = mbase + (t + 1) * 64;
#pragma unroll
      for (int i = 0; i < 4; ++i) {
        int off = tid * 16 + i * 8192;
        int c = off >> 7, inrow = off & 127;
        dma16(vbB + (size_t)c * (NSP * 2) + (size_t)m0 * 2 + inrow,
              (char*)Vs + off);
      }
    }
  }
  // ---- stats ----
  size_t sbase = ((size_t)kh * BB + b) * NSP + n0;
  if (quad == 0) {
    pm[sbase + w * 16 + l16] = m_run;
    pl[sbase + w * 16 + l16] = l_run;
  }
  // ---- epilogue: normalized bf16 O -> po [kh][b][n][c], LDS transpose ----
  float linv = 1.f / l_run;
  short* ob = po + ((size_t)kh * BB + b) * NSP * CCH;
#pragma unroll
  for (int p = 0; p < 2; ++p) {
    __syncthreads();
    if ((w >> 2) == p) {
      int nloc = (w & 3) * 16 + l16;
#pragma unroll
      for (int cb = 0; cb < 16; ++cb)
#pragma unroll
        for (int r = 0; r < 4; ++r)
          Fo[nloc * 264 + cb * 16 + quad * 4 + r] = f2bf(accO[cb][r] * linv);
    }
    __syncthreads();
    int row = tid >> 3, seg = tid & 7;
    short* dst = ob + (size_t)(n0 + p * 64 + row) * CCH + seg * 32;
#pragma unroll
    for (int i = 0; i < 4; ++i)
      *(bf16x8*)(dst + i * 8) = *(bf16x8*)(Fo + row * 264 + seg * 32 + i * 8);
  }
}

// ------- proj: frag-direct MFMA, KSPLIT-way merge in registers, +bias+resid -
__global__ __launch_bounds__(256) void proj_kernel(
    const short* __restrict__ po, const float* __restrict__ pm,
    const float* __restrict__ pl, const short* __restrict__ wpt,
    const float* __restrict__ bp, const float* __restrict__ x,
    float* __restrict__ out) {
  int n0 = blockIdx.x * 64;
  int dh = blockIdx.y * 128;
  int b = blockIdx.z;
  int tid = threadIdx.x;
  int w = tid >> 6, lane = tid & 63, quad = lane >> 4, l16 = lane & 15;
  int n = n0 + w * 16 + l16;

  float wgt[KSPLIT];
  {
    float m[KSPLIT];
    float M = -1e30f;
#pragma unroll
    for (int s = 0; s < KSPLIT; ++s) {
      m[s] = pm[((size_t)s * BB + b) * NSP + n];
      M = fmaxf(M, m[s]);
    }
    float wsum = 0.f;
#pragma unroll
    for (int s = 0; s < KSPLIT; ++s) {
      wgt[s] = __expf(m[s] - M) * pl[((size_t)s * BB + b) * NSP + n];
      wsum += wgt[s];
    }
    float linv = 1.f / wsum;
#pragma unroll
    for (int s = 0; s < KSPLIT; ++s) wgt[s] *= linv;
  }

  f32x4 acc[8];
#pragma unroll
  for (int mb = 0; mb < 8; ++mb) acc[mb] = (f32x4){0.f, 0.f, 0.f, 0.f};

  const short* pob = po + ((size_t)b * NSP + n) * CCH;
#pragma unroll 2
  for (int kc = 0; kc < 8; ++kc) {
    int coff = kc * 32 + quad * 8;
    float e[8];
#pragma unroll
    for (int i = 0; i < 8; ++i) e[i] = 0.f;
#pragma unroll
    for (int s = 0; s < KSPLIT; ++s) {
      bf16x8 f = *(const bf16x8*)(pob + (size_t)s * BB * NSP * CCH + coff);
#pragma unroll
      for (int i = 0; i < 8; ++i) e[i] += wgt[s] * bf2f(f[i]);
    }
    bf16x8 bm;
#pragma unroll
    for (int i = 0; i < 8; ++i) bm[i] = f2bf(e[i]);
#pragma unroll
    for (int mb = 0; mb < 8; ++mb) {
      bf16x8 af = *(const bf16x8*)(wpt + (size_t)(dh + mb * 16 + l16) * CCH + coff);
      acc[mb] = __builtin_amdgcn_mfma_f32_16x16x32_bf16(af, bm, acc[mb], 0, 0, 0);
    }
  }
#pragma unroll
  for (int mb = 0; mb < 8; ++mb) {
#pragma unroll
    for (int r = 0; r < 4; ++r) {
      int d = dh + mb * 16 + quad * 4 + r;
      size_t off = ((size_t)b * CCH + d) * NSP + n;
      out[off] = (acc[mb][r] + bp[d] + x[off]) * RSQRT2;
    }
  }
}

extern "C" void kernel_launch(void* const* d_in, const int* in_sizes, int n_in,
                              void* d_out, int out_size, void* d_ws, size_t ws_size,
                              hipStream_t stream) {
  const float* x  = (const float*)d_in[0];
  const float* gw = (const float*)d_in[1];
  const float* gb = (const float*)d_in[2];
  const float* Wq = (const float*)d_in[3];
  const float* bq = (const float*)d_in[4];
  const float* Wk = (const float*)d_in[5];
  const float* bk = (const float*)d_in[6];
  const float* Wv = (const float*)d_in[7];
  const float* bv = (const float*)d_in[8];
  const float* Wp = (const float*)d_in[9];
  const float* bp = (const float*)d_in[10];
  float* out = (float*)d_out;

  const size_t SZ = (size_t)BB * CCH * NSP;  // 4.19M elems
  short* qb  = (short*)d_ws;                 // bf16 [b][n][c] swizzled, scaled
  short* kb  = qb + SZ;                      // bf16 [b][n][c] swizzled
  short* vb  = kb + SZ;                      // bf16 [b][c][n] permuted
  short* poT = vb + SZ;                      // bf16 [KSPLIT][b][n][c] normalized
  float* pm  = (float*)(poT + (size_t)KSPLIT * SZ);  // [KSPLIT][b][n]
  float* pl  = pm + (size_t)KSPLIT * BB * NSP;
  float* stats = pl + (size_t)KSPLIT * BB * NSP;     // [b][32][2]
  short* wts = (short*)(stats + BB * 64);            // bf16 [4][256][256]
  short* wqt = wts;
  short* wkt = wts + (size_t)CCH * CCH;
  short* wvt = wts + (size_t)2 * CCH * CCH;
  short* wpt = wts + (size_t)3 * CCH * CCH;

  gn_stats<<<dim3(BB * 32), dim3(256), 0, stream>>>(x, stats);
  prep_w<<<dim3(4, 4, 4), dim3(256), 0, stream>>>(Wq, Wk, Wv, Wp, wts);
  qkvg_kernel<<<dim3(256), dim3(256), 0, stream>>>(
      x, stats, gw, gb, wqt, wkt, wvt, bq, bk, bv, qb, kb, vb);
  attn_kernel<<<dim3(BB * 32 * KSPLIT), dim3(512), 0, stream>>>(
      qb, kb, vb, poT, pm, pl);
  proj_kernel<<<dim3(64, 2, BB), dim3(256), 0, stream>>>(
      poT, pm, pl, wpt, bp, x, out);
}

// Round 4
// 282.896 us; speedup vs baseline: 1.1696x; 1.0215x over previous
//
#include <hip/hip_runtime.h>
#include <math.h>

// AttnBlock: GroupNorm(32) -> q,k,v 1x1 -> spatial attention -> proj -> resid.
// Round 13: cross-tile software pipeline in attn. K and V are double-buffered
// (128 KiB LDS total, 8-phase-template style); per tile ONE barrier (was 2),
// and QK(t+1) is computed in the same region as softmax(t)+PV(t) so its MFMAs
// fill the matrix pipe while the VALU runs softmax. DMA schedule (each
// target's last reader finished before the preceding barrier):
//   iter t top: K-DMA(t+2)->Ks[t&1], V-DMA(t+1)->Vs[(t+1)&1]
//   QK(t+1) reads Ks[(t+1)&1]; PV(t) reads Vs[t&1].
// Keeps R12's permuted-V full-rate PV, T13 defer-rescale, cvt_pk packing,
// setprio around MFMA clusters, DMA staging of pre-swizzled q/k/v.

#define BB 4
#define CCH 256
#define NSP 4096
#define EPSV 1e-5f
#define ATTN_SCALE 0.0625f  // 256^-0.5
#define RSQRT2 0.70710678118654752440f
#define KSPLIT 2
#define TILES_PER_PART 32   // 4096 / 64 / KSPLIT

typedef __attribute__((ext_vector_type(8))) short bf16x8;
typedef __attribute__((ext_vector_type(4))) float f32x4;

typedef __attribute__((address_space(1))) void gvoid;
typedef __attribute__((address_space(3))) void lvoid;
__device__ __forceinline__ void dma16(const void* g, void* l) {
  __builtin_amdgcn_global_load_lds((gvoid*)g, (lvoid*)l, 16, 0, 0);
}

__device__ __forceinline__ short f2bf(float f) {
  union { float f; unsigned u; } a; a.f = f;
  unsigned r = a.u + 0x7fffu + ((a.u >> 16) & 1u);  // RTN-even
  return (short)(r >> 16);
}
__device__ __forceinline__ float bf2f(short s) {
  union { unsigned u; float f; } a;
  a.u = ((unsigned)(unsigned short)s) << 16;
  return a.f;
}
__device__ __forceinline__ unsigned cvt_pk_bf16(float lo, float hi) {
  unsigned r;
  asm("v_cvt_pk_bf16_f32 %0, %1, %2" : "=v"(r) : "v"(lo), "v"(hi));
  return r;
}

// ---------------- GroupNorm stats only: mean/rstd per (b,g) ----------------
__global__ __launch_bounds__(256) void gn_stats(
    const float* __restrict__ x, float* __restrict__ stats) {
  int b = blockIdx.x >> 5;
  int g = blockIdx.x & 31;
  size_t base = ((size_t)b * CCH + (size_t)g * 8) * NSP;
  const float4* xv = (const float4*)(x + base);
  int tid = threadIdx.x;
  float s = 0.f, ss = 0.f;
  for (int i = tid; i < 8192; i += 256) {
    float4 v = xv[i];
    s += (v.x + v.y) + (v.z + v.w);
    ss += (v.x * v.x + v.y * v.y) + (v.z * v.z + v.w * v.w);
  }
#pragma unroll
  for (int off = 32; off > 0; off >>= 1) {
    s += __shfl_down(s, off, 64);
    ss += __shfl_down(ss, off, 64);
  }
  __shared__ float rs[4], rss[4];
  int wv = tid >> 6;
  if ((tid & 63) == 0) { rs[wv] = s; rss[wv] = ss; }
  __syncthreads();
  if (tid == 0) {
    float S = rs[0] + rs[1] + rs[2] + rs[3];
    float SS = rss[0] + rss[1] + rss[2] + rss[3];
    float mean = S * (1.f / 32768.f);
    float var = SS * (1.f / 32768.f) - mean * mean;
    stats[(b * 32 + g) * 2 + 0] = mean;
    stats[(b * 32 + g) * 2 + 1] = rsqrtf(var + EPSV);
  }
}

// ------------- prep: W [c][d] fp32 -> [d][c] bf16, 4 weights --------------
__global__ __launch_bounds__(256) void prep_w(
    const float* __restrict__ Wq, const float* __restrict__ Wk,
    const float* __restrict__ Wv, const float* __restrict__ Wp,
    short* __restrict__ wts) {
  __shared__ float T[64][65];
  int c0 = blockIdx.x * 64, d0 = blockIdx.y * 64;
  int wz = blockIdx.z;
  const float* W = (wz == 0) ? Wq : (wz == 1) ? Wk : (wz == 2) ? Wv : Wp;
  short* wt = wts + (size_t)wz * CCH * CCH;
  int tid = threadIdx.x;
#pragma unroll
  for (int i = 0; i < 16; ++i) {
    int idx = tid + 256 * i;
    int row = idx >> 6, col = idx & 63;
    T[row][col] = W[(size_t)(c0 + row) * CCH + d0 + col];
  }
  __syncthreads();
#pragma unroll
  for (int i = 0; i < 16; ++i) {
    int idx = tid + 256 * i;
    int dr = idx >> 6, cc = idx & 63;
    wt[(size_t)(d0 + dr) * CCH + c0 + cc] = f2bf(T[cc][dr]);
  }
}

// ------- qkvg: fused GN-apply + q,k,v projections via bf16 MFMA -----------
// q/k outputs chunk-swizzled for linear DMA into attn's LDS. v output [c][n]
// stores, within each 64-key tile, key mm at permuted position:
//   pk = ((mb&1)<<5)|(q<<3)|((mb>>1)<<2)|r   (mm = mb*16+q*4+r)
// then bank-swizzles the 8-key chunk by (c&7). This makes QK's s[mb][r]
// a direct 16x16x32 B-frag for PV (see attn_kernel).
__global__ __launch_bounds__(256) void qkvg_kernel(
    const float* __restrict__ x, const float* __restrict__ stats,
    const float* __restrict__ gw, const float* __restrict__ gb,
    const short* __restrict__ wqt, const short* __restrict__ wkt,
    const short* __restrict__ wvt,
    const float* __restrict__ bq, const float* __restrict__ bk,
    const float* __restrict__ bv,
    short* __restrict__ qo, short* __restrict__ ko, short* __restrict__ vo) {
  __shared__ __align__(16) unsigned char smem[52224];
  float (*Ts)[68] = (float(*)[68])smem;          // 64 x 68 fp32 (17408 B)
  float* aco = (float*)(smem + 17408);           // 256 f32
  float* bco = aco + 256;                        // 256 f32
  short* Hs = (short*)(smem + 19456);            // [64 n][256 c] swizzled bf16
  short* Fo = (short*)smem;                      // epilogue [64 n][264] bf16

  int bx = blockIdx.x;
  int b = bx & 3, n0 = (bx >> 2) * 64;
  int tid = threadIdx.x;
  {  // per-channel scale/shift
    int g = tid >> 3;
    float mean = stats[(b * 32 + g) * 2 + 0];
    float rstd = stats[(b * 32 + g) * 2 + 1];
    float a = gw[tid] * rstd;
    aco[tid] = a;
    bco[tid] = gb[tid] - mean * a;
  }
  __syncthreads();
  const float* xb = x + (size_t)b * CCH * NSP;
  // ---- 4 passes: load x chunk, normalize, transpose, bf16 -> swizzled Hs --
  for (int p = 0; p < 4; ++p) {
    int c0 = p * 64;
#pragma unroll
    for (int i = 0; i < 4; ++i) {
      int crow = (tid >> 4) + i * 16;
      int c = c0 + crow;
      float4 v = *(const float4*)&xb[(size_t)c * NSP + n0 + (tid & 15) * 4];
      float a = aco[c], bb = bco[c];
      v.x = v.x * a + bb; v.y = v.y * a + bb;
      v.z = v.z * a + bb; v.w = v.w * a + bb;
      *(float4*)&Ts[crow][(tid & 15) * 4] = v;   // Ts[c_local][n_local]
    }
    __syncthreads();
    {
      int n = tid >> 2, seg = tid & 3;
#pragma unroll
      for (int u = 0; u < 2; ++u) {
        int cb = seg * 16 + u * 8;
        bf16x8 r;
#pragma unroll
        for (int j = 0; j < 8; ++j) r[j] = f2bf(Ts[cb + j][n]);
        int chunk = (c0 + cb) >> 3;
        *(bf16x8*)(Hs + n * 256 + ((chunk ^ (n & 7)) * 8)) = r;
      }
    }
    __syncthreads();
  }
  // ---- extract B-frags (rows = this wave's 16 n) ----
  int w = tid >> 6, lane = tid & 63, quad = lane >> 4, l16 = lane & 15;
  bf16x8 a_h[8];
  {
    int row = w * 16 + l16;
#pragma unroll
    for (int kc = 0; kc < 8; ++kc)
      a_h[kc] = *(bf16x8*)(Hs + row * 256 + (((kc * 4 + quad) ^ (row & 7)) * 8));
  }
  __syncthreads();  // all waves extracted; smem reusable as Fo
  // ---- 3 projections ----
  for (int op = 0; op < 3; ++op) {
    const short* wt = (op == 0) ? wqt : (op == 1) ? wkt : wvt;
    const float* bias = (op == 0) ? bq : (op == 1) ? bk : bv;
    f32x4 acc[16];
#pragma unroll
    for (int mb = 0; mb < 16; ++mb) acc[mb] = (f32x4){0.f, 0.f, 0.f, 0.f};
#pragma unroll 4
    for (int mb = 0; mb < 16; ++mb) {
      const short* wp = wt + (size_t)(mb * 16 + l16) * CCH + quad * 8;
#pragma unroll
      for (int kc = 0; kc < 8; ++kc) {
        bf16x8 af = *(const bf16x8*)(wp + kc * 32);
        acc[mb] = __builtin_amdgcn_mfma_f32_16x16x32_bf16(af, a_h[kc], acc[mb], 0, 0, 0);
      }
    }
    int n = n0 + w * 16 + l16;
    if (op == 2) {  // v: [c][n-permuted] scalar stores
      short* ob = vo + (size_t)b * CCH * NSP;
      int mm = n & 63, m0_ = n & ~63;
      int mb_ = mm >> 4, qq = (mm >> 2) & 3, rr2 = mm & 3;
      int lc = (mb_ & 1) * 4 + qq;          // logical 8-key chunk
      int jj = (mb_ >> 1) * 4 + rr2;        // slot within chunk
      int basen = m0_ + jj;
#pragma unroll
      for (int mb = 0; mb < 16; ++mb)
#pragma unroll
        for (int r = 0; r < 4; ++r) {
          int d = mb * 16 + quad * 4 + r;
          ob[(size_t)d * NSP + basen + ((lc ^ (d & 7)) << 3)] =
              f2bf(acc[mb][r] + bias[d]);
        }
    } else {  // q/k: transpose via Fo -> [n][c] b128 stores, chunk-swizzled
      float sc = (op == 0) ? ATTN_SCALE : 1.f;
      int nl = w * 16 + l16;
#pragma unroll
      for (int mb = 0; mb < 16; ++mb)
#pragma unroll
        for (int r = 0; r < 4; ++r) {
          int d = mb * 16 + quad * 4 + r;
          Fo[nl * 264 + d] = f2bf((acc[mb][r] + bias[d]) * sc);
        }
      __syncthreads();
      short* ob = ((op == 0) ? qo : ko) + (size_t)b * NSP * CCH;
#pragma unroll
      for (int it = 0; it < 2; ++it) {
        int idx = tid + 256 * it;
        int row = idx >> 3, seg = idx & 7, r7 = row & 7;
        short* dst = ob + (size_t)(n0 + row) * CCH + seg * 32;
#pragma unroll
        for (int i = 0; i < 4; ++i) {
          int xch = seg * 4 + i;
          int cs = (xch & 24) | ((xch & 7) ^ r7);  // source chunk for slot xch
          *(bf16x8*)(dst + i * 8) = *(bf16x8*)(Fo + row * 264 + cs * 8);
        }
      }
      __syncthreads();
    }
  }
}

// ------ flash attention: 8 waves, 16 q/wave, 128 q/block, pipelined --------
// q,k: [b][n][c] bf16 chunk-swizzled (q pre-scaled); v: [b][c][n] bf16
// key-permuted + chunk-swizzled. K,V double-buffered (128 KiB LDS); one
// barrier per tile; QK(t+1) overlaps softmax(t)+PV(t).
__global__ __launch_bounds__(512, 1) void attn_kernel(
    const short* __restrict__ q, const short* __restrict__ k,
    const short* __restrict__ v, short* __restrict__ po,
    float* __restrict__ pm, float* __restrict__ pl) {
  __shared__ __align__(16) unsigned char smem[131072];  // 128 KB
  short* Ks0 = (short*)smem;             // K even tiles / Q stage
  short* Ks1 = (short*)(smem + 32768);   // K odd tiles
  short* Vs0 = (short*)(smem + 65536);   // V even tiles
  short* Vs1 = (short*)(smem + 98304);   // V odd tiles
  short* Fo  = (short*)smem;             // epilogue [64 n][264 c] bf16

  int bx = blockIdx.x;
  int b = bx & 3;
  int n0 = ((bx >> 2) & 31) << 7;   // 128-query block
  int kh = bx >> 7;                 // key half
  const short* qb = q + (size_t)b * NSP * CCH;
  const short* kb = k + (size_t)b * NSP * CCH;
  const char*  vbB = (const char*)(v + (size_t)b * CCH * NSP);
  int tid = threadIdx.x;
  int w = tid >> 6, lane = tid & 63, quad = lane >> 4, l16 = lane & 15;
  int mbase = kh * TILES_PER_PART * 64;

  // ---- stage Q in 2 passes of 64 rows through Ks0; extract B-frags ----
  bf16x8 a_q[8];
#pragma unroll
  for (int p = 0; p < 2; ++p) {
#pragma unroll
    for (int i = 0; i < 4; ++i) {
      int off = tid * 16 + i * 8192;
      dma16((const char*)(qb + (size_t)(n0 + p * 64) * CCH) + off,
            (char*)Ks0 + off);
    }
    __syncthreads();
    if ((w >> 2) == p) {
      int row = (w & 3) * 16 + l16;
#pragma unroll
      for (int kc = 0; kc < 8; ++kc)
        a_q[kc] = *(bf16x8*)(Ks0 + row * 256 + (((kc * 4 + quad) ^ (row & 7)) * 8));
    }
    __syncthreads();
  }

  // ---- prologue: K0->Ks0, V0->Vs0; drain; K1->Ks1; QK(0) ----
#pragma unroll
  for (int i = 0; i < 4; ++i) {
    int off = tid * 16 + i * 8192;
    dma16((const char*)(kb + (size_t)mbase * CCH) + off, (char*)Ks0 + off);
    int c = off >> 7, inrow = off & 127;
    dma16(vbB + (size_t)c * (NSP * 2) + (size_t)mbase * 2 + inrow,
          (char*)Vs0 + off);
  }
  __syncthreads();
#pragma unroll
  for (int i = 0; i < 4; ++i) {
    int off = tid * 16 + i * 8192;
    dma16((const char*)(kb + (size_t)(mbase + 64) * CCH) + off,
          (char*)Ks1 + off);
  }
  f32x4 s_prev[4];
#pragma unroll
  for (int mb = 0; mb < 4; ++mb) s_prev[mb] = (f32x4){0.f, 0.f, 0.f, 0.f};
  __builtin_amdgcn_s_setprio(1);
#pragma unroll
  for (int kc = 0; kc < 8; ++kc) {
#pragma unroll
    for (int mb = 0; mb < 4; ++mb) {
      int row = mb * 16 + l16;
      bf16x8 kf = *(bf16x8*)(Ks0 + row * 256 + (((kc * 4 + quad) ^ (row & 7)) * 8));
      s_prev[mb] = __builtin_amdgcn_mfma_f32_16x16x32_bf16(kf, a_q[kc], s_prev[mb], 0, 0, 0);
    }
  }
  __builtin_amdgcn_s_setprio(0);

  f32x4 accO[16];  // O^T C-layout: ch = cb*16 + quad*4 + r, query = w*16+l16
#pragma unroll
  for (int cb = 0; cb < 16; ++cb) accO[cb] = (f32x4){0.f, 0.f, 0.f, 0.f};
  float m_run = -1e30f, l_run = 0.f;
  int pc0 = quad ^ (l16 & 7);        // V chunk for key-group 0 (loop-invariant)
  int pc1 = (4 + quad) ^ (l16 & 7);  // key-group 1

#pragma unroll 1
  for (int t = 0; t < TILES_PER_PART; ++t) {
    __syncthreads();  // DMA(issued last iter) complete; buffers' readers done
    short* Kd = (t & 1) ? Ks1 : Ks0;   // dest for K(t+2)
    short* Kr = (t & 1) ? Ks0 : Ks1;   // source for QK(t+1)
    short* Vd = (t & 1) ? Vs0 : Vs1;   // dest for V(t+1)
    short* Vr = (t & 1) ? Vs1 : Vs0;   // source for PV(t)
    if (t + 2 < TILES_PER_PART) {      // K-DMA(t+2): last read by QK(t) prev iter
      const char* kp = (const char*)(kb + (size_t)(mbase + (t + 2) * 64) * CCH);
#pragma unroll
      for (int i = 0; i < 4; ++i) {
        int off = tid * 16 + i * 8192;
        dma16(kp + off, (char*)Kd + off);
      }
    }
    if (t + 1 < TILES_PER_PART) {      // V-DMA(t+1): last read by PV(t-1)
      int m0 = mbase + (t + 1) * 64;
#pragma unroll
      for (int i = 0; i < 4; ++i) {
        int off = tid * 16 + i * 8192;
        int c = off >> 7, inrow = off & 127;
        dma16(vbB + (size_t)c * (NSP * 2) + (size_t)m0 * 2 + inrow,
              (char*)Vd + off);
      }
    }
    // ---- QK(t+1): independent MFMA stream, fills pipe under softmax(t) ----
    f32x4 sn[4];
#pragma unroll
    for (int mb = 0; mb < 4; ++mb) sn[mb] = (f32x4){0.f, 0.f, 0.f, 0.f};
    if (t + 1 < TILES_PER_PART) {
      __builtin_amdgcn_s_setprio(1);
#pragma unroll
      for (int kc = 0; kc < 8; ++kc) {
#pragma unroll
        for (int mb = 0; mb < 4; ++mb) {
          int row = mb * 16 + l16;
          bf16x8 kf = *(bf16x8*)(Kr + row * 256 + (((kc * 4 + quad) ^ (row & 7)) * 8));
          sn[mb] = __builtin_amdgcn_mfma_f32_16x16x32_bf16(kf, a_q[kc], sn[mb], 0, 0, 0);
        }
      }
      __builtin_amdgcn_s_setprio(0);
    }
    // ---- online softmax(t) on s_prev: per-lane scalar stats ----
    float mx = -1e30f;
#pragma unroll
    for (int mb = 0; mb < 4; ++mb)
#pragma unroll
      for (int r = 0; r < 4; ++r) mx = fmaxf(mx, s_prev[mb][r]);
    mx = fmaxf(mx, __shfl_xor(mx, 16));
    mx = fmaxf(mx, __shfl_xor(mx, 32));
    if (!__all(mx - m_run <= 8.f)) {   // T13: rescale only when max grows >8
      float mnew = fmaxf(m_run, mx);
      float alpha = __expf(m_run - mnew);
#pragma unroll
      for (int cb = 0; cb < 16; ++cb) accO[cb] *= alpha;
      l_run *= alpha;
      m_run = mnew;
    }
    float ls = 0.f;
#pragma unroll
    for (int mb = 0; mb < 4; ++mb)
#pragma unroll
      for (int r = 0; r < 4; ++r) {
        float p = __expf(s_prev[mb][r] - m_run);   // bounded by e^8
        ls += p;
        s_prev[mb][r] = p;
      }
    ls += __shfl_xor(ls, 16);
    ls += __shfl_xor(ls, 32);
    l_run += ls;
    // ---- pack P into 16x16x32 B-frags (key permutation makes this direct) --
    union { unsigned u[4]; bf16x8 v; } pw0, pw1;
    pw0.u[0] = cvt_pk_bf16(s_prev[0][0], s_prev[0][1]);
    pw0.u[1] = cvt_pk_bf16(s_prev[0][2], s_prev[0][3]);
    pw0.u[2] = cvt_pk_bf16(s_prev[2][0], s_prev[2][1]);
    pw0.u[3] = cvt_pk_bf16(s_prev[2][2], s_prev[2][3]);
    pw1.u[0] = cvt_pk_bf16(s_prev[1][0], s_prev[1][1]);
    pw1.u[1] = cvt_pk_bf16(s_prev[1][2], s_prev[1][3]);
    pw1.u[2] = cvt_pk_bf16(s_prev[3][0], s_prev[3][1]);
    pw1.u[3] = cvt_pk_bf16(s_prev[3][2], s_prev[3][3]);
    // ---- O^T += V P^T : full-rate 16x16x32, b128 V reads ----
    __builtin_amdgcn_s_setprio(1);
#pragma unroll
    for (int cb = 0; cb < 16; ++cb) {
      bf16x8 vf = *(bf16x8*)(Vr + (cb * 16 + l16) * 64 + pc0 * 8);
      accO[cb] = __builtin_amdgcn_mfma_f32_16x16x32_bf16(vf, pw0.v, accO[cb], 0, 0, 0);
    }
#pragma unroll
    for (int cb = 0; cb < 16; ++cb) {
      bf16x8 vf = *(bf16x8*)(Vr + (cb * 16 + l16) * 64 + pc1 * 8);
      accO[cb] = __builtin_amdgcn_mfma_f32_16x16x32_bf16(vf, pw1.v, accO[cb], 0, 0, 0);
    }
    __builtin_amdgcn_s_setprio(0);
    // ---- roll S ----
#pragma unroll
    for (int mb = 0; mb < 4; ++mb) s_prev[mb] = sn[mb];
  }
  // ---- stats ----
  size_t sbase = ((size_t)kh * BB + b) * NSP + n0;
  if (quad == 0) {
    pm[sbase + w * 16 + l16] = m_run;
    pl[sbase + w * 16 + l16] = l_run;
  }
  // ---- epilogue: normalized bf16 O -> po [kh][b][n][c], LDS transpose ----
  float linv = 1.f / l_run;
  short* ob = po + ((size_t)kh * BB + b) * NSP * CCH;
#pragma unroll
  for (int p = 0; p < 2; ++p) {
    __syncthreads();
    if ((w >> 2) == p) {
      int nloc = (w & 3) * 16 + l16;
#pragma unroll
      for (int cb = 0; cb < 16; ++cb)
#pragma unroll
        for (int r = 0; r < 4; ++r)
          Fo[nloc * 264 + cb * 16 + quad * 4 + r] = f2bf(accO[cb][r] * linv);
    }
    __syncthreads();
    int row = tid >> 3, seg = tid & 7;
    short* dst = ob + (size_t)(n0 + p * 64 + row) * CCH + seg * 32;
#pragma unroll
    for (int i = 0; i < 4; ++i)
      *(bf16x8*)(dst + i * 8) = *(bf16x8*)(Fo + row * 264 + seg * 32 + i * 8);
  }
}

// ------- proj: frag-direct MFMA, KSPLIT-way merge in registers, +bias+resid -
__global__ __launch_bounds__(256) void proj_kernel(
    const short* __restrict__ po, const float* __restrict__ pm,
    const float* __restrict__ pl, const short* __restrict__ wpt,
    const float* __restrict__ bp, const float* __restrict__ x,
    float* __restrict__ out) {
  int n0 = blockIdx.x * 64;
  int dh = blockIdx.y * 128;
  int b = blockIdx.z;
  int tid = threadIdx.x;
  int w = tid >> 6, lane = tid & 63, quad = lane >> 4, l16 = lane & 15;
  int n = n0 + w * 16 + l16;

  float wgt[KSPLIT];
  {
    float m[KSPLIT];
    float M = -1e30f;
#pragma unroll
    for (int s = 0; s < KSPLIT; ++s) {
      m[s] = pm[((size_t)s * BB + b) * NSP + n];
      M = fmaxf(M, m[s]);
    }
    float wsum = 0.f;
#pragma unroll
    for (int s = 0; s < KSPLIT; ++s) {
      wgt[s] = __expf(m[s] - M) * pl[((size_t)s * BB + b) * NSP + n];
      wsum += wgt[s];
    }
    float linv = 1.f / wsum;
#pragma unroll
    for (int s = 0; s < KSPLIT; ++s) wgt[s] *= linv;
  }

  f32x4 acc[8];
#pragma unroll
  for (int mb = 0; mb < 8; ++mb) acc[mb] = (f32x4){0.f, 0.f, 0.f, 0.f};

  const short* pob = po + ((size_t)b * NSP + n) * CCH;
#pragma unroll 2
  for (int kc = 0; kc < 8; ++kc) {
    int coff = kc * 32 + quad * 8;
    float e[8];
#pragma unroll
    for (int i = 0; i < 8; ++i) e[i] = 0.f;
#pragma unroll
    for (int s = 0; s < KSPLIT; ++s) {
      bf16x8 f = *(const bf16x8*)(pob + (size_t)s * BB * NSP * CCH + coff);
#pragma unroll
      for (int i = 0; i < 8; ++i) e[i] += wgt[s] * bf2f(f[i]);
    }
    bf16x8 bm;
#pragma unroll
    for (int i = 0; i < 8; ++i) bm[i] = f2bf(e[i]);
#pragma unroll
    for (int mb = 0; mb < 8; ++mb) {
      bf16x8 af = *(const bf16x8*)(wpt + (size_t)(dh + mb * 16 + l16) * CCH + coff);
      acc[mb] = __builtin_amdgcn_mfma_f32_16x16x32_bf16(af, bm, acc[mb], 0, 0, 0);
    }
  }
#pragma unroll
  for (int mb = 0; mb < 8; ++mb) {
#pragma unroll
    for (int r = 0; r < 4; ++r) {
      int d = dh + mb * 16 + quad * 4 + r;
      size_t off = ((size_t)b * CCH + d) * NSP + n;
      out[off] = (acc[mb][r] + bp[d] + x[off]) * RSQRT2;
    }
  }
}

extern "C" void kernel_launch(void* const* d_in, const int* in_sizes, int n_in,
                              void* d_out, int out_size, void* d_ws, size_t ws_size,
                              hipStream_t stream) {
  const float* x  = (const float*)d_in[0];
  const float* gw = (const float*)d_in[1];
  const float* gb = (const float*)d_in[2];
  const float* Wq = (const float*)d_in[3];
  const float* bq = (const float*)d_in[4];
  const float* Wk = (const float*)d_in[5];
  const float* bk = (const float*)d_in[6];
  const float* Wv = (const float*)d_in[7];
  const float* bv = (const float*)d_in[8];
  const float* Wp = (const float*)d_in[9];
  const float* bp = (const float*)d_in[10];
  float* out = (float*)d_out;

  const size_t SZ = (size_t)BB * CCH * NSP;  // 4.19M elems
  short* qb  = (short*)d_ws;                 // bf16 [b][n][c] swizzled, scaled
  short* kb  = qb + SZ;                      // bf16 [b][n][c] swizzled
  short* vb  = kb + SZ;                      // bf16 [b][c][n] permuted
  short* poT = vb + SZ;                      // bf16 [KSPLIT][b][n][c] normalized
  float* pm  = (float*)(poT + (size_t)KSPLIT * SZ);  // [KSPLIT][b][n]
  float* pl  = pm + (size_t)KSPLIT * BB * NSP;
  float* stats = pl + (size_t)KSPLIT * BB * NSP;     // [b][32][2]
  short* wts = (short*)(stats + BB * 64);            // bf16 [4][256][256]
  short* wqt = wts;
  short* wkt = wts + (size_t)CCH * CCH;
  short* wvt = wts + (size_t)2 * CCH * CCH;
  short* wpt = wts + (size_t)3 * CCH * CCH;

  gn_stats<<<dim3(BB * 32), dim3(256), 0, stream>>>(x, stats);
  prep_w<<<dim3(4, 4, 4), dim3(256), 0, stream>>>(Wq, Wk, Wv, Wp, wts);
  qkvg_kernel<<<dim3(256), dim3(256), 0, stream>>>(
      x, stats, gw, gb, wqt, wkt, wvt, bq, bk, bv, qb, kb, vb);
  attn_kernel<<<dim3(BB * 32 * KSPLIT), dim3(512), 0, stream>>>(
      qb, kb, vb, poT, pm, pl);
  proj_kernel<<<dim3(64, 2, BB), dim3(256), 0, stream>>>(
      poT, pm, pl, wpt, bp, x, out);
}

// Round 5
// 275.423 us; speedup vs baseline: 1.2014x; 1.0271x over previous
//
#include <hip/hip_runtime.h>
#include <math.h>

// AttnBlock: GroupNorm(32) -> q,k,v 1x1 -> spatial attention -> proj -> resid.
// Round 14: (1) XCD-group swizzle in attn: there are exactly 8 (b,kh) groups
// and 8 XCDs; mapping group = bid&7 (= XCD under round-robin dispatch) makes
// each XCD's K/V working set one 2MB K-half + 2MB V-half = 4MB = its L2.
// K/V tile re-reads (5.2 TB/s chip-wide) move from Infinity Cache to L2.
// (2) mx reduction for tile t+1 hoisted to end of iter t (shuffle latency
// hides under the barrier). (3) qkvg: 512 threads / 8 waves, waves split the
// output-d space (halved acc regs, 2 waves/SIMD instead of 1).

#define BB 4
#define CCH 256
#define NSP 4096
#define EPSV 1e-5f
#define ATTN_SCALE 0.0625f  // 256^-0.5
#define RSQRT2 0.70710678118654752440f
#define KSPLIT 2
#define TILES_PER_PART 32   // 4096 / 64 / KSPLIT

typedef __attribute__((ext_vector_type(8))) short bf16x8;
typedef __attribute__((ext_vector_type(4))) float f32x4;

typedef __attribute__((address_space(1))) void gvoid;
typedef __attribute__((address_space(3))) void lvoid;
__device__ __forceinline__ void dma16(const void* g, void* l) {
  __builtin_amdgcn_global_load_lds((gvoid*)g, (lvoid*)l, 16, 0, 0);
}

__device__ __forceinline__ short f2bf(float f) {
  union { float f; unsigned u; } a; a.f = f;
  unsigned r = a.u + 0x7fffu + ((a.u >> 16) & 1u);  // RTN-even
  return (short)(r >> 16);
}
__device__ __forceinline__ float bf2f(short s) {
  union { unsigned u; float f; } a;
  a.u = ((unsigned)(unsigned short)s) << 16;
  return a.f;
}
__device__ __forceinline__ unsigned cvt_pk_bf16(float lo, float hi) {
  unsigned r;
  asm("v_cvt_pk_bf16_f32 %0, %1, %2" : "=v"(r) : "v"(lo), "v"(hi));
  return r;
}

// ---------------- GroupNorm stats only: mean/rstd per (b,g) ----------------
__global__ __launch_bounds__(256) void gn_stats(
    const float* __restrict__ x, float* __restrict__ stats) {
  int b = blockIdx.x >> 5;
  int g = blockIdx.x & 31;
  size_t base = ((size_t)b * CCH + (size_t)g * 8) * NSP;
  const float4* xv = (const float4*)(x + base);
  int tid = threadIdx.x;
  float s = 0.f, ss = 0.f;
  for (int i = tid; i < 8192; i += 256) {
    float4 v = xv[i];
    s += (v.x + v.y) + (v.z + v.w);
    ss += (v.x * v.x + v.y * v.y) + (v.z * v.z + v.w * v.w);
  }
#pragma unroll
  for (int off = 32; off > 0; off >>= 1) {
    s += __shfl_down(s, off, 64);
    ss += __shfl_down(ss, off, 64);
  }
  __shared__ float rs[4], rss[4];
  int wv = tid >> 6;
  if ((tid & 63) == 0) { rs[wv] = s; rss[wv] = ss; }
  __syncthreads();
  if (tid == 0) {
    float S = rs[0] + rs[1] + rs[2] + rs[3];
    float SS = rss[0] + rss[1] + rss[2] + rss[3];
    float mean = S * (1.f / 32768.f);
    float var = SS * (1.f / 32768.f) - mean * mean;
    stats[(b * 32 + g) * 2 + 0] = mean;
    stats[(b * 32 + g) * 2 + 1] = rsqrtf(var + EPSV);
  }
}

// ------------- prep: W [c][d] fp32 -> [d][c] bf16, 4 weights --------------
__global__ __launch_bounds__(256) void prep_w(
    const float* __restrict__ Wq, const float* __restrict__ Wk,
    const float* __restrict__ Wv, const float* __restrict__ Wp,
    short* __restrict__ wts) {
  __shared__ float T[64][65];
  int c0 = blockIdx.x * 64, d0 = blockIdx.y * 64;
  int wz = blockIdx.z;
  const float* W = (wz == 0) ? Wq : (wz == 1) ? Wk : (wz == 2) ? Wv : Wp;
  short* wt = wts + (size_t)wz * CCH * CCH;
  int tid = threadIdx.x;
#pragma unroll
  for (int i = 0; i < 16; ++i) {
    int idx = tid + 256 * i;
    int row = idx >> 6, col = idx & 63;
    T[row][col] = W[(size_t)(c0 + row) * CCH + d0 + col];
  }
  __syncthreads();
#pragma unroll
  for (int i = 0; i < 16; ++i) {
    int idx = tid + 256 * i;
    int dr = idx >> 6, cc = idx & 63;
    wt[(size_t)(d0 + dr) * CCH + c0 + cc] = f2bf(T[cc][dr]);
  }
}

// ------- qkvg: fused GN-apply + q,k,v projections via bf16 MFMA -----------
// 512 threads / 8 waves: wave w handles rows (w&3)*16.. and d-half (w>>2).
// q/k outputs chunk-swizzled for linear DMA into attn's LDS. v output [c][n]
// stores, within each 64-key tile, key mm at permuted position
// pk = ((mb&1)<<5)|(q<<3)|((mb>>1)<<2)|r, then bank-swizzled by (c&7).
__global__ __launch_bounds__(512) void qkvg_kernel(
    const float* __restrict__ x, const float* __restrict__ stats,
    const float* __restrict__ gw, const float* __restrict__ gb,
    const short* __restrict__ wqt, const short* __restrict__ wkt,
    const short* __restrict__ wvt,
    const float* __restrict__ bq, const float* __restrict__ bk,
    const float* __restrict__ bv,
    short* __restrict__ qo, short* __restrict__ ko, short* __restrict__ vo) {
  __shared__ __align__(16) unsigned char smem[52224];
  float (*Ts)[68] = (float(*)[68])smem;          // 64 x 68 fp32 (17408 B)
  float* aco = (float*)(smem + 17408);           // 256 f32
  float* bco = aco + 256;                        // 256 f32
  short* Hs = (short*)(smem + 19456);            // [64 n][256 c] swizzled bf16
  short* Fo = (short*)smem;                      // epilogue [64 n][264] bf16

  int bx = blockIdx.x;
  int b = bx & 3, n0 = (bx >> 2) * 64;
  int tid = threadIdx.x;
  if (tid < 256) {  // per-channel scale/shift
    int g = tid >> 3;
    float mean = stats[(b * 32 + g) * 2 + 0];
    float rstd = stats[(b * 32 + g) * 2 + 1];
    float a = gw[tid] * rstd;
    aco[tid] = a;
    bco[tid] = gb[tid] - mean * a;
  }
  __syncthreads();
  const float* xb = x + (size_t)b * CCH * NSP;
  // ---- 4 passes: load x chunk, normalize, transpose, bf16 -> swizzled Hs --
  for (int p = 0; p < 4; ++p) {
    int c0 = p * 64;
#pragma unroll
    for (int i = 0; i < 2; ++i) {
      int crow = (tid >> 4) + i * 32;
      int c = c0 + crow;
      float4 v = *(const float4*)&xb[(size_t)c * NSP + n0 + (tid & 15) * 4];
      float a = aco[c], bb = bco[c];
      v.x = v.x * a + bb; v.y = v.y * a + bb;
      v.z = v.z * a + bb; v.w = v.w * a + bb;
      *(float4*)&Ts[crow][(tid & 15) * 4] = v;   // Ts[c_local][n_local]
    }
    __syncthreads();
    {
      int n = tid >> 3, seg = tid & 7;
      int cb = seg * 8;
      bf16x8 r;
#pragma unroll
      for (int j = 0; j < 8; ++j) r[j] = f2bf(Ts[cb + j][n]);
      int chunk = (c0 + cb) >> 3;
      *(bf16x8*)(Hs + n * 256 + ((chunk ^ (n & 7)) * 8)) = r;
    }
    __syncthreads();
  }
  // ---- extract B-frags (rows = this wave's 16 n) ----
  int w = tid >> 6, lane = tid & 63, quad = lane >> 4, l16 = lane & 15;
  int wr = w & 3, h = w >> 2;  // row-group, d-half
  bf16x8 a_h[8];
  {
    int row = wr * 16 + l16;
#pragma unroll
    for (int kc = 0; kc < 8; ++kc)
      a_h[kc] = *(bf16x8*)(Hs + row * 256 + (((kc * 4 + quad) ^ (row & 7)) * 8));
  }
  __syncthreads();  // all waves extracted; smem reusable as Fo
  // ---- 3 projections; wave handles d in [h*128, h*128+128) ----
  for (int op = 0; op < 3; ++op) {
    const short* wt = (op == 0) ? wqt : (op == 1) ? wkt : wvt;
    const float* bias = (op == 0) ? bq : (op == 1) ? bk : bv;
    f32x4 acc[8];
#pragma unroll
    for (int mb = 0; mb < 8; ++mb) acc[mb] = (f32x4){0.f, 0.f, 0.f, 0.f};
#pragma unroll 4
    for (int mb = 0; mb < 8; ++mb) {
      const short* wp = wt + (size_t)((h * 8 + mb) * 16 + l16) * CCH + quad * 8;
#pragma unroll
      for (int kc = 0; kc < 8; ++kc) {
        bf16x8 af = *(const bf16x8*)(wp + kc * 32);
        acc[mb] = __builtin_amdgcn_mfma_f32_16x16x32_bf16(af, a_h[kc], acc[mb], 0, 0, 0);
      }
    }
    int n = n0 + wr * 16 + l16;
    if (op == 2) {  // v: [c][n-permuted] scalar stores
      short* ob = vo + (size_t)b * CCH * NSP;
      int mm = n & 63, m0_ = n & ~63;
      int mb_ = mm >> 4, qq = (mm >> 2) & 3, rr2 = mm & 3;
      int lc = (mb_ & 1) * 4 + qq;          // logical 8-key chunk
      int jj = (mb_ >> 1) * 4 + rr2;        // slot within chunk
      int basen = m0_ + jj;
#pragma unroll
      for (int mb = 0; mb < 8; ++mb)
#pragma unroll
        for (int r = 0; r < 4; ++r) {
          int d = (h * 8 + mb) * 16 + quad * 4 + r;
          ob[(size_t)d * NSP + basen + ((lc ^ (d & 7)) << 3)] =
              f2bf(acc[mb][r] + bias[d]);
        }
    } else {  // q/k: transpose via Fo -> [n][c] b128 stores, chunk-swizzled
      float sc = (op == 0) ? ATTN_SCALE : 1.f;
      int nl = wr * 16 + l16;
#pragma unroll
      for (int mb = 0; mb < 8; ++mb)
#pragma unroll
        for (int r = 0; r < 4; ++r) {
          int d = (h * 8 + mb) * 16 + quad * 4 + r;
          Fo[nl * 264 + d] = f2bf((acc[mb][r] + bias[d]) * sc);
        }
      __syncthreads();
      short* ob = ((op == 0) ? qo : ko) + (size_t)b * NSP * CCH;
      {
        int row = tid >> 3, seg = tid & 7, r7 = row & 7;
        short* dst = ob + (size_t)(n0 + row) * CCH + seg * 32;
#pragma unroll
        for (int i = 0; i < 4; ++i) {
          int xch = seg * 4 + i;
          int cs = (xch & 24) | ((xch & 7) ^ r7);  // source chunk for slot xch
          *(bf16x8*)(dst + i * 8) = *(bf16x8*)(Fo + row * 264 + cs * 8);
        }
      }
      __syncthreads();
    }
  }
}

// ------ flash attention: 8 waves, 16 q/wave, 128 q/block, pipelined --------
// XCD-group swizzle: group (b,kh) = bid&7 so each XCD's 32 CUs share one
// 2MB K-half + 2MB V-half = 4MB = its private L2.
__global__ __launch_bounds__(512, 1) void attn_kernel(
    const short* __restrict__ q, const short* __restrict__ k,
    const short* __restrict__ v, short* __restrict__ po,
    float* __restrict__ pm, float* __restrict__ pl) {
  __shared__ __align__(16) unsigned char smem[131072];  // 128 KB
  short* Ks0 = (short*)smem;             // K even tiles / Q stage
  short* Ks1 = (short*)(smem + 32768);   // K odd tiles
  short* Vs0 = (short*)(smem + 65536);   // V even tiles
  short* Vs1 = (short*)(smem + 98304);   // V odd tiles
  short* Fo  = (short*)smem;             // epilogue [64 n][264 c] bf16

  int bx = blockIdx.x;
  int grp = bx & 7;                 // XCD id under round-robin dispatch
  int b = grp & 3;
  int kh = grp >> 2;                // key half
  int n0 = ((bx >> 3) & 31) << 7;   // 128-query block
  const short* qb = q + (size_t)b * NSP * CCH;
  const short* kb = k + (size_t)b * NSP * CCH;
  const char*  vbB = (const char*)(v + (size_t)b * CCH * NSP);
  int tid = threadIdx.x;
  int w = tid >> 6, lane = tid & 63, quad = lane >> 4, l16 = lane & 15;
  int mbase = kh * TILES_PER_PART * 64;

  // ---- stage Q in 2 passes of 64 rows through Ks0; extract B-frags ----
  bf16x8 a_q[8];
#pragma unroll
  for (int p = 0; p < 2; ++p) {
#pragma unroll
    for (int i = 0; i < 4; ++i) {
      int off = tid * 16 + i * 8192;
      dma16((const char*)(qb + (size_t)(n0 + p * 64) * CCH) + off,
            (char*)Ks0 + off);
    }
    __syncthreads();
    if ((w >> 2) == p) {
      int row = (w & 3) * 16 + l16;
#pragma unroll
      for (int kc = 0; kc < 8; ++kc)
        a_q[kc] = *(bf16x8*)(Ks0 + row * 256 + (((kc * 4 + quad) ^ (row & 7)) * 8));
    }
    __syncthreads();
  }

  // ---- prologue: K0->Ks0, V0->Vs0; drain; K1->Ks1; QK(0) ----
#pragma unroll
  for (int i = 0; i < 4; ++i) {
    int off = tid * 16 + i * 8192;
    dma16((const char*)(kb + (size_t)mbase * CCH) + off, (char*)Ks0 + off);
    int c = off >> 7, inrow = off & 127;
    dma16(vbB + (size_t)c * (NSP * 2) + (size_t)mbase * 2 + inrow,
          (char*)Vs0 + off);
  }
  __syncthreads();
#pragma unroll
  for (int i = 0; i < 4; ++i) {
    int off = tid * 16 + i * 8192;
    dma16((const char*)(kb + (size_t)(mbase + 64) * CCH) + off,
          (char*)Ks1 + off);
  }
  f32x4 s_prev[4];
#pragma unroll
  for (int mb = 0; mb < 4; ++mb) s_prev[mb] = (f32x4){0.f, 0.f, 0.f, 0.f};
  __builtin_amdgcn_s_setprio(1);
#pragma unroll
  for (int kc = 0; kc < 8; ++kc) {
#pragma unroll
    for (int mb = 0; mb < 4; ++mb) {
      int row = mb * 16 + l16;
      bf16x8 kf = *(bf16x8*)(Ks0 + row * 256 + (((kc * 4 + quad) ^ (row & 7)) * 8));
      s_prev[mb] = __builtin_amdgcn_mfma_f32_16x16x32_bf16(kf, a_q[kc], s_prev[mb], 0, 0, 0);
    }
  }
  __builtin_amdgcn_s_setprio(0);
  // carried cross-lane max of s_prev (reduction latency hidden here)
  float mx_c = -1e30f;
#pragma unroll
  for (int mb = 0; mb < 4; ++mb)
#pragma unroll
    for (int r = 0; r < 4; ++r) mx_c = fmaxf(mx_c, s_prev[mb][r]);
  mx_c = fmaxf(mx_c, __shfl_xor(mx_c, 16));
  mx_c = fmaxf(mx_c, __shfl_xor(mx_c, 32));

  f32x4 accO[16];  // O^T C-layout: ch = cb*16 + quad*4 + r, query = w*16+l16
#pragma unroll
  for (int cb = 0; cb < 16; ++cb) accO[cb] = (f32x4){0.f, 0.f, 0.f, 0.f};
  float m_run = -1e30f, l_run = 0.f;
  int pc0 = quad ^ (l16 & 7);        // V chunk for key-group 0 (loop-invariant)
  int pc1 = (4 + quad) ^ (l16 & 7);  // key-group 1

#pragma unroll 1
  for (int t = 0; t < TILES_PER_PART; ++t) {
    __syncthreads();  // DMA(issued last iter) complete; buffers' readers done
    short* Kd = (t & 1) ? Ks1 : Ks0;   // dest for K(t+2)
    short* Kr = (t & 1) ? Ks0 : Ks1;   // source for QK(t+1)
    short* Vd = (t & 1) ? Vs0 : Vs1;   // dest for V(t+1)
    short* Vr = (t & 1) ? Vs1 : Vs0;   // source for PV(t)
    if (t + 2 < TILES_PER_PART) {      // K-DMA(t+2): last read by QK(t) prev iter
      const char* kp = (const char*)(kb + (size_t)(mbase + (t + 2) * 64) * CCH);
#pragma unroll
      for (int i = 0; i < 4; ++i) {
        int off = tid * 16 + i * 8192;
        dma16(kp + off, (char*)Kd + off);
      }
    }
    if (t + 1 < TILES_PER_PART) {      // V-DMA(t+1): last read by PV(t-1)
      int m0 = mbase + (t + 1) * 64;
#pragma unroll
      for (int i = 0; i < 4; ++i) {
        int off = tid * 16 + i * 8192;
        int c = off >> 7, inrow = off & 127;
        dma16(vbB + (size_t)c * (NSP * 2) + (size_t)m0 * 2 + inrow,
              (char*)Vd + off);
      }
    }
    // ---- QK(t+1): independent MFMA stream, fills pipe under softmax(t) ----
    f32x4 sn[4];
#pragma unroll
    for (int mb = 0; mb < 4; ++mb) sn[mb] = (f32x4){0.f, 0.f, 0.f, 0.f};
    if (t + 1 < TILES_PER_PART) {
      __builtin_amdgcn_s_setprio(1);
#pragma unroll
      for (int kc = 0; kc < 8; ++kc) {
#pragma unroll
        for (int mb = 0; mb < 4; ++mb) {
          int row = mb * 16 + l16;
          bf16x8 kf = *(bf16x8*)(Kr + row * 256 + (((kc * 4 + quad) ^ (row & 7)) * 8));
          sn[mb] = __builtin_amdgcn_mfma_f32_16x16x32_bf16(kf, a_q[kc], sn[mb], 0, 0, 0);
        }
      }
      __builtin_amdgcn_s_setprio(0);
    }
    // ---- online softmax(t) on s_prev, using carried mx_c ----
    if (!__all(mx_c - m_run <= 8.f)) {   // T13: rescale only when max grows >8
      float mnew = fmaxf(m_run, mx_c);
      float alpha = __expf(m_run - mnew);
#pragma unroll
      for (int cb = 0; cb < 16; ++cb) accO[cb] *= alpha;
      l_run *= alpha;
      m_run = mnew;
    }
    float ls = 0.f;
#pragma unroll
    for (int mb = 0; mb < 4; ++mb)
#pragma unroll
      for (int r = 0; r < 4; ++r) {
        float p = __expf(s_prev[mb][r] - m_run);   // bounded by e^8
        ls += p;
        s_prev[mb][r] = p;
      }
    ls += __shfl_xor(ls, 16);
    ls += __shfl_xor(ls, 32);
    l_run += ls;
    // ---- pack P into 16x16x32 B-frags (key permutation makes this direct) --
    union { unsigned u[4]; bf16x8 v; } pw0, pw1;
    pw0.u[0] = cvt_pk_bf16(s_prev[0][0], s_prev[0][1]);
    pw0.u[1] = cvt_pk_bf16(s_prev[0][2], s_prev[0][3]);
    pw0.u[2] = cvt_pk_bf16(s_prev[2][0], s_prev[2][1]);
    pw0.u[3] = cvt_pk_bf16(s_prev[2][2], s_prev[2][3]);
    pw1.u[0] = cvt_pk_bf16(s_prev[1][0], s_prev[1][1]);
    pw1.u[1] = cvt_pk_bf16(s_prev[1][2], s_prev[1][3]);
    pw1.u[2] = cvt_pk_bf16(s_prev[3][0], s_prev[3][1]);
    pw1.u[3] = cvt_pk_bf16(s_prev[3][2], s_prev[3][3]);
    // ---- O^T += V P^T : full-rate 16x16x32, b128 V reads ----
    __builtin_amdgcn_s_setprio(1);
#pragma unroll
    for (int cb = 0; cb < 16; ++cb) {
      bf16x8 vf = *(bf16x8*)(Vr + (cb * 16 + l16) * 64 + pc0 * 8);
      accO[cb] = __builtin_amdgcn_mfma_f32_16x16x32_bf16(vf, pw0.v, accO[cb], 0, 0, 0);
    }
#pragma unroll
    for (int cb = 0; cb < 16; ++cb) {
      bf16x8 vf = *(bf16x8*)(Vr + (cb * 16 + l16) * 64 + pc1 * 8);
      accO[cb] = __builtin_amdgcn_mfma_f32_16x16x32_bf16(vf, pw1.v, accO[cb], 0, 0, 0);
    }
    __builtin_amdgcn_s_setprio(0);
    // ---- next-tile max (latency hides under barrier + next QK) ----
    if (t + 1 < TILES_PER_PART) {
      float mxn = -1e30f;
#pragma unroll
      for (int mb = 0; mb < 4; ++mb)
#pragma unroll
        for (int r = 0; r < 4; ++r) mxn = fmaxf(mxn, sn[mb][r]);
      mxn = fmaxf(mxn, __shfl_xor(mxn, 16));
      mxn = fmaxf(mxn, __shfl_xor(mxn, 32));
      mx_c = mxn;
    }
    // ---- roll S ----
#pragma unroll
    for (int mb = 0; mb < 4; ++mb) s_prev[mb] = sn[mb];
  }
  // ---- stats ----
  size_t sbase = ((size_t)kh * BB + b) * NSP + n0;
  if (quad == 0) {
    pm[sbase + w * 16 + l16] = m_run;
    pl[sbase + w * 16 + l16] = l_run;
  }
  // ---- epilogue: normalized bf16 O -> po [kh][b][n][c], LDS transpose ----
  float linv = 1.f / l_run;
  short* ob = po + ((size_t)kh * BB + b) * NSP * CCH;
#pragma unroll
  for (int p = 0; p < 2; ++p) {
    __syncthreads();
    if ((w >> 2) == p) {
      int nloc = (w & 3) * 16 + l16;
#pragma unroll
      for (int cb = 0; cb < 16; ++cb)
#pragma unroll
        for (int r = 0; r < 4; ++r)
          Fo[nloc * 264 + cb * 16 + quad * 4 + r] = f2bf(accO[cb][r] * linv);
    }
    __syncthreads();
    int row = tid >> 3, seg = tid & 7;
    short* dst = ob + (size_t)(n0 + p * 64 + row) * CCH + seg * 32;
#pragma unroll
    for (int i = 0; i < 4; ++i)
      *(bf16x8*)(dst + i * 8) = *(bf16x8*)(Fo + row * 264 + seg * 32 + i * 8);
  }
}

// ------- proj: frag-direct MFMA, KSPLIT-way merge in registers, +bias+resid -
__global__ __launch_bounds__(256) void proj_kernel(
    const short* __restrict__ po, const float* __restrict__ pm,
    const float* __restrict__ pl, const short* __restrict__ wpt,
    const float* __restrict__ bp, const float* __restrict__ x,
    float* __restrict__ out) {
  int n0 = blockIdx.x * 64;
  int dh = blockIdx.y * 128;
  int b = blockIdx.z;
  int tid = threadIdx.x;
  int w = tid >> 6, lane = tid & 63, quad = lane >> 4, l16 = lane & 15;
  int n = n0 + w * 16 + l16;

  float wgt[KSPLIT];
  {
    float m[KSPLIT];
    float M = -1e30f;
#pragma unroll
    for (int s = 0; s < KSPLIT; ++s) {
      m[s] = pm[((size_t)s * BB + b) * NSP + n];
      M = fmaxf(M, m[s]);
    }
    float wsum = 0.f;
#pragma unroll
    for (int s = 0; s < KSPLIT; ++s) {
      wgt[s] = __expf(m[s] - M) * pl[((size_t)s * BB + b) * NSP + n];
      wsum += wgt[s];
    }
    float linv = 1.f / wsum;
#pragma unroll
    for (int s = 0; s < KSPLIT; ++s) wgt[s] *= linv;
  }

  f32x4 acc[8];
#pragma unroll
  for (int mb = 0; mb < 8; ++mb) acc[mb] = (f32x4){0.f, 0.f, 0.f, 0.f};

  const short* pob = po + ((size_t)b * NSP + n) * CCH;
#pragma unroll 2
  for (int kc = 0; kc < 8; ++kc) {
    int coff = kc * 32 + quad * 8;
    float e[8];
#pragma unroll
    for (int i = 0; i < 8; ++i) e[i] = 0.f;
#pragma unroll
    for (int s = 0; s < KSPLIT; ++s) {
      bf16x8 f = *(const bf16x8*)(pob + (size_t)s * BB * NSP * CCH + coff);
#pragma unroll
      for (int i = 0; i < 8; ++i) e[i] += wgt[s] * bf2f(f[i]);
    }
    bf16x8 bm;
#pragma unroll
    for (int i = 0; i < 8; ++i) bm[i] = f2bf(e[i]);
#pragma unroll
    for (int mb = 0; mb < 8; ++mb) {
      bf16x8 af = *(const bf16x8*)(wpt + (size_t)(dh + mb * 16 + l16) * CCH + coff);
      acc[mb] = __builtin_amdgcn_mfma_f32_16x16x32_bf16(af, bm, acc[mb], 0, 0, 0);
    }
  }
#pragma unroll
  for (int mb = 0; mb < 8; ++mb) {
#pragma unroll
    for (int r = 0; r < 4; ++r) {
      int d = dh + mb * 16 + quad * 4 + r;
      size_t off = ((size_t)b * CCH + d) * NSP + n;
      out[off] = (acc[mb][r] + bp[d] + x[off]) * RSQRT2;
    }
  }
}

extern "C" void kernel_launch(void* const* d_in, const int* in_sizes, int n_in,
                              void* d_out, int out_size, void* d_ws, size_t ws_size,
                              hipStream_t stream) {
  const float* x  = (const float*)d_in[0];
  const float* gw = (const float*)d_in[1];
  const float* gb = (const float*)d_in[2];
  const float* Wq = (const float*)d_in[3];
  const float* bq = (const float*)d_in[4];
  const float* Wk = (const float*)d_in[5];
  const float* bk = (const float*)d_in[6];
  const float* Wv = (const float*)d_in[7];
  const float* bv = (const float*)d_in[8];
  const float* Wp = (const float*)d_in[9];
  const float* bp = (const float*)d_in[10];
  float* out = (float*)d_out;

  const size_t SZ = (size_t)BB * CCH * NSP;  // 4.19M elems
  short* qb  = (short*)d_ws;                 // bf16 [b][n][c] swizzled, scaled
  short* kb  = qb + SZ;                      // bf16 [b][n][c] swizzled
  short* vb  = kb + SZ;                      // bf16 [b][c][n] permuted
  short* poT = vb + SZ;                      // bf16 [KSPLIT][b][n][c] normalized
  float* pm  = (float*)(poT + (size_t)KSPLIT * SZ);  // [KSPLIT][b][n]
  float* pl  = pm + (size_t)KSPLIT * BB * NSP;
  float* stats = pl + (size_t)KSPLIT * BB * NSP;     // [b][32][2]
  short* wts = (short*)(stats + BB * 64);            // bf16 [4][256][256]
  short* wqt = wts;
  short* wkt = wts + (size_t)CCH * CCH;
  short* wvt = wts + (size_t)2 * CCH * CCH;
  short* wpt = wts + (size_t)3 * CCH * CCH;

  gn_stats<<<dim3(BB * 32), dim3(256), 0, stream>>>(x, stats);
  prep_w<<<dim3(4, 4, 4), dim3(256), 0, stream>>>(Wq, Wk, Wv, Wp, wts);
  qkvg_kernel<<<dim3(256), dim3(512), 0, stream>>>(
      x, stats, gw, gb, wqt, wkt, wvt, bq, bk, bv, qb, kb, vb);
  attn_kernel<<<dim3(BB * 32 * KSPLIT), dim3(512), 0, stream>>>(
      qb, kb, vb, poT, pm, pl);
  proj_kernel<<<dim3(64, 2, BB), dim3(256), 0, stream>>>(
      poT, pm, pl, wpt, bp, x, out);
}